// Round 11
// baseline (1298.060 us; speedup 1.0000x reference)
//
#include <hip/hip_runtime.h>
#include <math.h>

#define N_NODES 100000
#define N_HEDGES 200000
#define N_INC 1000000
#define N_GRAPHS 256
#define HD 64
#define HE 35
#define CAT 99
#define EPSB 1e-5f

typedef __attribute__((ext_vector_type(8))) short short8;
typedef __attribute__((ext_vector_type(4))) float f32x4;

__device__ __forceinline__ float sp_f(float x) {
  return fmaxf(x, 0.f) + __logf(1.f + __expf(-fabsf(x)));
}
__device__ __forceinline__ float sig_f(float x) {
  return __builtin_amdgcn_rcpf(1.f + __expf(-x));
}
__device__ __forceinline__ unsigned bfr(float x) {
  unsigned u = __float_as_uint(x);
  return (u + 0x7fffu + ((u >> 16) & 1u)) >> 16;
}
__device__ __forceinline__ unsigned pk2(float lo, float hi) {
  return bfr(lo) | (bfr(hi) << 16);
}
__device__ __forceinline__ float blo(unsigned v) { return __uint_as_float(v << 16); }
__device__ __forceinline__ float bhi(unsigned v) {
  return __uint_as_float(v & 0xffff0000u);
}
__device__ __forceinline__ float bf2f(unsigned short s) {
  return __uint_as_float(((unsigned)s) << 16);
}

// ---- histogram + within-segment ranks ----
__global__ __launch_bounds__(256) void k_hist(const int* __restrict__ nidx,
                                              const int* __restrict__ hidx,
                                              int* __restrict__ degN,
                                              int* __restrict__ degH,
                                              int* __restrict__ rankN,
                                              int* __restrict__ rankH) {
  int e = blockIdx.x * 256 + threadIdx.x;
  if (e >= N_INC) return;
  rankH[e] = atomicAdd(&degH[hidx[e]], 1);
  rankN[e] = atomicAdd(&degN[nidx[e]], 1);
}

#define CHB ((N_HEDGES + 255) / 256)
#define CNB ((N_NODES + 255) / 256)

// ---- per-256-chunk degree sums (both segmentations) ----
__global__ __launch_bounds__(256) void k_bsum(const int* __restrict__ degH,
                                              const int* __restrict__ degN,
                                              int* __restrict__ bsum) {
  __shared__ int s[256];
  int b = blockIdx.x, t = threadIdx.x;
  const int* deg;
  int n, i;
  if (b < CHB) {
    deg = degH; n = N_HEDGES; i = b * 256 + t;
  } else {
    deg = degN; n = N_NODES; i = (b - CHB) * 256 + t;
  }
  s[t] = (i < n) ? deg[i] : 0;
  __syncthreads();
  for (int st = 128; st > 0; st >>= 1) {
    if (t < st) s[t] += s[t + st];
    __syncthreads();
  }
  if (t == 0) bsum[b] = s[0];
}

// ---- exclusive scan of chunk sums, per segment ----
__global__ __launch_bounds__(64) void k_bscan(int* __restrict__ bsum) {
  int seg0 = (blockIdx.x == 0) ? 0 : CHB;
  int segn = (blockIdx.x == 0) ? CHB : CNB;
  int lane = threadIdx.x;
  int carry = 0;
  for (int base = 0; base < segn; base += 64) {
    int i = base + lane;
    int orig = (i < segn) ? bsum[seg0 + i] : 0;
    int v = orig;
    for (int st = 1; st < 64; st <<= 1) {
      int u = __shfl_up(v, st);
      if (lane >= st) v += u;
    }
    int total = __shfl(v, 63);
    if (i < segn) bsum[seg0 + i] = carry + (v - orig);
    carry += total;
  }
}

// ---- ordered CSR offsets ----
__global__ __launch_bounds__(256) void k_alloc2(const int* __restrict__ degH,
                                                const int* __restrict__ degN,
                                                const int* __restrict__ bsum,
                                                int* __restrict__ offH,
                                                int* __restrict__ offN,
                                                float* __restrict__ invdH) {
  __shared__ int s[256];
  int b = blockIdx.x, t = threadIdx.x;
  const int* deg;
  int* off;
  int n, i;
  bool isH = (b < CHB);
  if (isH) {
    deg = degH; off = offH; n = N_HEDGES; i = b * 256 + t;
  } else {
    deg = degN; off = offN; n = N_NODES; i = (b - CHB) * 256 + t;
  }
  int d = (i < n) ? deg[i] : 0;
  s[t] = d;
  __syncthreads();
  for (int st = 1; st < 256; st <<= 1) {
    int u = 0;
    if (t >= st) u = s[t - st];
    __syncthreads();
    if (t >= st) s[t] += u;
    __syncthreads();
  }
  if (i < n) {
    off[i] = s[t] - d + bsum[b];
    if (isH) invdH[i] = 1.f / (float)max(d, 1);
  }
}

// ---- atomic-free CSR fill (+ offH sentinel) ----
__global__ __launch_bounds__(256) void k_fill(const int* __restrict__ nidx,
                                              const int* __restrict__ hidx,
                                              const int* __restrict__ rankH,
                                              const int* __restrict__ rankN,
                                              const int* __restrict__ offH,
                                              const int* __restrict__ offN,
                                              int* __restrict__ permHn,
                                              int* __restrict__ permNh,
                                              int* __restrict__ offH_sent) {
  int e = blockIdx.x * 256 + threadIdx.x;
  if (e >= N_INC) return;
  if (e == 0) *offH_sent = N_INC;  // offH[N_HEDGES]
  int nd = nidx[e], hg = hidx[e];
  permHn[offH[hg] + rankH[e]] = nd;
  permNh[offN[nd] + rankN[e]] = hg;
}

// ---- weight prepack: B[k=0..127][col=0..79] = [Wf | Wc | pad] as MFMA B-frags ----
__global__ __launch_bounds__(64) void k_wpack(const float* __restrict__ f1w,
                                              const float* __restrict__ c1w,
                                              uint4* __restrict__ wpk) {
  int b = blockIdx.x;  // 60 = 3 layers * 5 ct * 4 ks
  int layer = b / 20, rem = b % 20, ct = rem / 4, ks = rem % 4;
  int lane = threadIdx.x;
  int col = ct * 16 + (lane & 15);
  int k0 = ks * 32 + (lane >> 4) * 8;
  const float* wf = f1w + layer * CAT * HE;
  const float* wc = c1w + layer * CAT * HE;
  unsigned v[4];
#pragma unroll
  for (int p = 0; p < 4; ++p) {
    float lo = 0.f, hi = 0.f;
    int ka = k0 + p * 2, kb = ka + 1;
    if (ka < 99) {
      if (col < 35) lo = wf[ka * 35 + col];
      else if (col >= 36 && col < 71) lo = wc[ka * 35 + (col - 36)];
    }
    if (kb < 99) {
      if (col < 35) hi = wf[kb * 35 + col];
      else if (col >= 36 && col < 71) hi = wc[kb * 35 + (col - 36)];
    }
    v[p] = pk2(lo, hi);
  }
  uint4 o;
  o.x = v[0]; o.y = v[1]; o.z = v[2]; o.w = v[3];
  wpk[b * 64 + lane] = o;
}

// ---- hedge_attr f32 -> bf16 once ----
__global__ __launch_bounds__(256) void k_cvt_ha(const float* __restrict__ src,
                                                unsigned short* __restrict__ dst,
                                                int n) {
  int t = blockIdx.x * 256 + threadIdx.x;
  if (t < n) dst[t] = (unsigned short)bfr(src[t]);
}

// -------------------- embed: x[N,92] @ w[92,64] + b -> bf16 --------------------
__global__ __launch_bounds__(256) void k_embed(const float* __restrict__ x,
                                               const float* __restrict__ w,
                                               const float* __restrict__ b,
                                               unsigned short* __restrict__ outb) {
  __shared__ float ws[92 * 64];
  __shared__ float rs[16][93];
  int tid = threadIdx.x;
  for (int i = tid; i < 92 * 64; i += 256) ws[i] = w[i];
  int r0 = blockIdx.x * 16;
  for (int i = tid; i < 16 * 92; i += 256) {
    int r = i / 92, k = i - r * 92;
    rs[r][k] = x[(r0 + r) * 92 + k];
  }
  __syncthreads();
  int h = tid & 63;
  float bias = b[h];
  for (int rr = tid >> 6; rr < 16; rr += 4) {
    float acc = bias;
    for (int k = 0; k < 92; ++k) acc += rs[rr][k] * ws[k * 64 + h];
    outb[(r0 + rr) * 64 + h] = (unsigned short)bfr(acc);
  }
}

// ------ FUSED hedge gather (linear-entry, software-pipelined) + MFMA GEMM ------
// GR=64 (exactly divides 200000). 256 thr (4 waves); wave w owns rows
// w*16..w*16+15 = contiguous perm range [offH[r0w], offH[r0w+16]).
// Pipelined chunk walk: prefetch chunk t+1's 8 values (wave-uniform branch,
// unconditional clustered loads) BEFORE accumulating chunk t.
// msg LDS [64][128] bf16, swizzled byte ^= (row&7)<<4.
#define GR 64
__global__ __launch_bounds__(256) void k_hedge_gemm(
    const unsigned short* __restrict__ xb, const int* __restrict__ permHn,
    const int* __restrict__ offH, const float* __restrict__ invdH,
    const unsigned short* __restrict__ hab, const uint4* __restrict__ wpk,
    unsigned short* __restrict__ z, float* __restrict__ stats) {
  __shared__ unsigned short msg[GR * 128];
  __shared__ float ps[160];
  __shared__ int bndL[4][18];
  int tid = threadIdx.x;
  int w = tid >> 6, lane = tid & 63;
  int r0 = blockIdx.x * GR;
  if (tid < 160) ps[tid] = 0.f;

  // B-fragments (L2-resident)
  short8 bfg[5][4];
#pragma unroll
  for (int ct = 0; ct < 5; ++ct)
#pragma unroll
    for (int ks = 0; ks < 4; ++ks)
      bfg[ct][ks] = __builtin_bit_cast(short8, wpk[(ct * 4 + ks) * 64 + lane]);

  char* mb = (char*)msg;
  // cooperative hab staging into msg cols 64..127 (zero-padded past 98)
  for (int i = tid; i < GR * 64; i += 256) {
    int r = i >> 6, c = 64 + (i & 63);
    unsigned short hv = 0;
    if (c < 99) hv = hab[(size_t)(r0 + r) * 35 + (c - 64)];
    *(unsigned short*)(mb + ((r * 256 + c * 2) ^ ((r & 7) << 4))) = hv;
  }

  // per-wave row bounds (17 values; offH has sentinel at N_HEDGES)
  int r0w = r0 + w * 16;
  if (lane < 17) bndL[w][lane] = offH[r0w + lane];
  int eBeg = bndL[w][0], eEnd = bndL[w][16];

  float v0, v1, v2, v3, v4, v5, v6, v7;
  float n0, n1, n2, n3, n4, n5, n6, n7;
#define LOADCH(chunk, a0, a1, a2, a3, a4, a5, a6, a7)                        \
  {                                                                          \
    int i0 = permHn[min((chunk) + 0, eEnd - 1)];                             \
    int i1 = permHn[min((chunk) + 1, eEnd - 1)];                             \
    int i2 = permHn[min((chunk) + 2, eEnd - 1)];                             \
    int i3 = permHn[min((chunk) + 3, eEnd - 1)];                             \
    int i4 = permHn[min((chunk) + 4, eEnd - 1)];                             \
    int i5 = permHn[min((chunk) + 5, eEnd - 1)];                             \
    int i6 = permHn[min((chunk) + 6, eEnd - 1)];                             \
    int i7 = permHn[min((chunk) + 7, eEnd - 1)];                             \
    a0 = bf2f(xb[(size_t)i0 * 64 + lane]);                                   \
    a1 = bf2f(xb[(size_t)i1 * 64 + lane]);                                   \
    a2 = bf2f(xb[(size_t)i2 * 64 + lane]);                                   \
    a3 = bf2f(xb[(size_t)i3 * 64 + lane]);                                   \
    a4 = bf2f(xb[(size_t)i4 * 64 + lane]);                                   \
    a5 = bf2f(xb[(size_t)i5 * 64 + lane]);                                   \
    a6 = bf2f(xb[(size_t)i6 * 64 + lane]);                                   \
    a7 = bf2f(xb[(size_t)i7 * 64 + lane]);                                   \
  }

  int j = 0;
  int nb = bndL[w][1];
  float acc = 0.f;
  if (eBeg < eEnd) LOADCH(eBeg, v0, v1, v2, v3, v4, v5, v6, v7);
  for (int chunk = eBeg; chunk < eEnd; chunk += 8) {
    // prefetch next chunk (wave-uniform branch; clustered unconditional loads)
    if (chunk + 8 < eEnd) LOADCH(chunk + 8, n0, n1, n2, n3, n4, n5, n6, n7);
    // accumulate current chunk with run-boundary flushes (overlaps prefetch)
#pragma unroll
    for (int t = 0; t < 8; ++t) {
      int e = chunk + t;
      if (e >= eEnd) break;
      while (e >= nb) {  // flush completed row j (wave-uniform)
        int rl = w * 16 + j;
        unsigned short mv = (unsigned short)bfr(acc * invdH[r0w + j]);
        *(unsigned short*)(mb + ((rl * 256 + lane * 2) ^ ((rl & 7) << 4))) = mv;
        acc = 0.f;
        ++j;
        nb = bndL[w][j + 1];
      }
      float vt = (t == 0) ? v0 : (t == 1) ? v1 : (t == 2) ? v2 : (t == 3) ? v3
                 : (t == 4) ? v4 : (t == 5) ? v5 : (t == 6) ? v6 : v7;
      acc += vt;
    }
    v0 = n0; v1 = n1; v2 = n2; v3 = n3; v4 = n4; v5 = n5; v6 = n6; v7 = n7;
  }
  for (; j < 16; ++j) {  // tail flush (incl. empty rows)
    int rl = w * 16 + j;
    unsigned short mv = (unsigned short)bfr(acc * invdH[r0w + j]);
    *(unsigned short*)(mb + ((rl * 256 + lane * 2) ^ ((rl & 7) << 4))) = mv;
    acc = 0.f;
  }
#undef LOADCH
  __syncthreads();

  // MFMA + stats + bf16 Z write (one 16-row tile per wave)
  {
    int rloc = w * 16 + (lane & 15);
    short8 a[4];
#pragma unroll
    for (int ks = 0; ks < 4; ++ks) {
      int byte = rloc * 256 + (ks * 32 + (lane >> 4) * 8) * 2;
      a[ks] = *(const short8*)(mb + (byte ^ ((rloc & 7) << 4)));
    }
#pragma unroll
    for (int ct = 0; ct < 5; ++ct) {
      f32x4 acc4 = {0.f, 0.f, 0.f, 0.f};
#pragma unroll
      for (int ks = 0; ks < 4; ++ks)
        acc4 = __builtin_amdgcn_mfma_f32_16x16x32_bf16(a[ks], bfg[ct][ks], acc4, 0, 0, 0);
      float s = (acc4[0] + acc4[1]) + (acc4[2] + acc4[3]);
      float q = (acc4[0] * acc4[0] + acc4[1] * acc4[1]) +
                (acc4[2] * acc4[2] + acc4[3] * acc4[3]);
      s += __shfl_xor(s, 16);
      s += __shfl_xor(s, 32);
      q += __shfl_xor(q, 16);
      q += __shfl_xor(q, 32);
      int col = ct * 16 + (lane & 15);
      if ((lane >> 4) == 0 && col < 72) {
        atomicAdd(&ps[col], s);
        atomicAdd(&ps[80 + col], q);
      }
      int growb = r0 + w * 16 + ((lane >> 4) << 2);
      if (col < 72) {
#pragma unroll
        for (int r = 0; r < 4; ++r)
          z[(size_t)(growb + r) * 72 + col] = (unsigned short)bfr(acc4[r]);
      }
    }
  }
  __syncthreads();
  if (tid < 160) atomicAdd(&stats[tid], ps[tid]);
}

// ---- FUSED: BN+act over Z -> ha (bf16, global) AND V = ha @ W2b + bias -> Vfc ----
__global__ __launch_bounds__(256) void k_hedge_post(
    const unsigned short* __restrict__ z, const float* __restrict__ stats,
    const float* __restrict__ gf, const float* __restrict__ bf_,
    const float* __restrict__ gc, const float* __restrict__ bc_,
    const float* __restrict__ f2wb, const float* __restrict__ c2wb,
    const float* __restrict__ f2b, const float* __restrict__ c2b,
    unsigned short* __restrict__ hab, unsigned* __restrict__ Vfc) {
  __shared__ float wf[35 * 64];
  __shared__ float wc[35 * 64];
  __shared__ float rs[16][36];
  __shared__ float sf[4][35];  // scaleF, shiftF, scaleC, shiftC
  int tid = threadIdx.x;
  for (int i = tid; i < 35 * 64; i += 256) {
    wf[i] = f2wb[i];
    wc[i] = c2wb[i];
  }
  if (tid < 35) {
    const float inv = 1.f / N_HEDGES;
    float mf = stats[tid] * inv;
    float vf = stats[80 + tid] * inv - mf * mf;
    float mc = stats[36 + tid] * inv;
    float vc = stats[116 + tid] * inv - mc * mc;
    float a = rsqrtf(vf + EPSB) * gf[tid];
    float b = rsqrtf(vc + EPSB) * gc[tid];
    sf[0][tid] = a;
    sf[1][tid] = bf_[tid] - mf * a;
    sf[2][tid] = b;
    sf[3][tid] = bc_[tid] - mc * b;
  }
  __syncthreads();
  int r0 = blockIdx.x * 16;
  for (int i = tid; i < 16 * 35; i += 256) {
    int r = i / 35, c = i - r * 35;
    const unsigned short* zr = &z[(size_t)(r0 + r) * 72];
    float nf = bf2f(zr[c]) * sf[0][c] + sf[1][c];
    float nc = bf2f(zr[36 + c]) * sf[2][c] + sf[3][c];
    float ha = sig_f(nf) * sp_f(nc);
    rs[r][c] = ha;
    hab[(size_t)(r0 + r) * 35 + c] = (unsigned short)bfr(ha);
  }
  __syncthreads();
  int h = tid & 63, rb = tid >> 6;
  float af0, af1, af2, af3, ac0, ac1, ac2, ac3;
  af0 = af1 = af2 = af3 = f2b[h];
  ac0 = ac1 = ac2 = ac3 = c2b[h];
  for (int k = 0; k < 35; ++k) {
    float wfv = wf[k * 64 + h], wcv = wc[k * 64 + h];
    float m0 = rs[rb][k], m1 = rs[rb + 4][k], m2 = rs[rb + 8][k], m3 = rs[rb + 12][k];
    af0 += m0 * wfv; ac0 += m0 * wcv;
    af1 += m1 * wfv; ac1 += m1 * wcv;
    af2 += m2 * wfv; ac2 += m2 * wcv;
    af3 += m3 * wfv; ac3 += m3 * wcv;
  }
  int row = r0 + rb;
  Vfc[row * 64 + h] = pk2(af0, ac0);
  Vfc[(row + 4) * 64 + h] = pk2(af1, ac1);
  Vfc[(row + 8) * 64 + h] = pk2(af2, ac2);
  Vfc[(row + 12) * 64 + h] = pk2(af3, ac3);
}

// ---- per-node projection: U = x @ W[0:64,:], bf16 in, packed bf16x2 out ----
__global__ __launch_bounds__(256) void k_uv_node(const unsigned short* __restrict__ xb,
                                                 const float* __restrict__ f2w,
                                                 const float* __restrict__ c2w,
                                                 unsigned* __restrict__ Ufc) {
  __shared__ float wf[64 * 64];
  __shared__ float wc[64 * 64];
  __shared__ float rs[16][65];
  int tid = threadIdx.x;
  for (int i = tid; i < 64 * 64; i += 256) {
    wf[i] = f2w[i];
    wc[i] = c2w[i];
  }
  int r0 = blockIdx.x * 16;
  for (int i = tid; i < 16 * 64; i += 256) {
    int r = i >> 6, k = i & 63;
    rs[r][k] = bf2f(xb[(size_t)(r0 + r) * 64 + k]);
  }
  __syncthreads();
  int h = tid & 63, rb = tid >> 6;
  float af0 = 0, af1 = 0, af2 = 0, af3 = 0, ac0 = 0, ac1 = 0, ac2 = 0, ac3 = 0;
  for (int k = 0; k < 64; ++k) {
    float wfv = wf[k * 64 + h], wcv = wc[k * 64 + h];
    float m0 = rs[rb][k], m1 = rs[rb + 4][k], m2 = rs[rb + 8][k], m3 = rs[rb + 12][k];
    af0 += m0 * wfv; ac0 += m0 * wcv;
    af1 += m1 * wfv; ac1 += m1 * wcv;
    af2 += m2 * wfv; ac2 += m2 * wcv;
    af3 += m3 * wfv; ac3 += m3 * wcv;
  }
  int row = r0 + rb;
  Ufc[row * 64 + h] = pk2(af0, ac0);
  Ufc[(row + 4) * 64 + h] = pk2(af1, ac1);
  Ufc[(row + 8) * 64 + h] = pk2(af2, ac2);
  Ufc[(row + 12) * 64 + h] = pk2(af3, ac3);
}

// ------ per-node aggregate + fused BN stats (grid-stride, block-reduced) ------
__device__ __forceinline__ float act2(float uf, float uc, unsigned v) {
  float a = uf + blo(v);
  float b = uc + bhi(v);
  return sig_f(a) * sp_f(b);
}
#define NAGG_GRID 2048
__global__ __launch_bounds__(256) void k_node_aggr(const int* __restrict__ permNh,
                                                   const int* __restrict__ offN,
                                                   const int* __restrict__ degN,
                                                   const unsigned* __restrict__ Ufc,
                                                   const unsigned* __restrict__ Vfc,
                                                   float* __restrict__ o,
                                                   float* __restrict__ stats) {
  int tid = threadIdx.x;
  int h = tid & 63, sub = tid >> 6;
  float sacc = 0.f, qacc = 0.f;
  for (int grp = blockIdx.x; grp < N_NODES / 4; grp += NAGG_GRID) {
    int wid = grp * 4 + sub;
    int off = offN[wid], d = degN[wid];
    unsigned u = Ufc[wid * 64 + h];
    float uf = blo(u), uc = bhi(u);
    float acc = 0.f;
    int k = 0;
    for (; k + 4 <= d; k += 4) {
      int h0 = permNh[off + k], h1 = permNh[off + k + 1];
      int h2 = permNh[off + k + 2], h3 = permNh[off + k + 3];
      unsigned v0 = Vfc[h0 * 64 + h];
      unsigned v1 = Vfc[h1 * 64 + h];
      unsigned v2 = Vfc[h2 * 64 + h];
      unsigned v3 = Vfc[h3 * 64 + h];
      acc += (act2(uf, uc, v0) + act2(uf, uc, v1)) +
             (act2(uf, uc, v2) + act2(uf, uc, v3));
    }
    for (; k < d; ++k) acc += act2(uf, uc, Vfc[permNh[off + k] * 64 + h]);
    float val = acc / (float)max(d, 1);
    o[(size_t)wid * 64 + h] = val;
    sacc += val;
    qacc += val * val;
  }
  __shared__ float ls[2][4][64];
  ls[0][sub][h] = sacc;
  ls[1][sub][h] = qacc;
  __syncthreads();
  if (tid < 64) {
    atomicAdd(&stats[h], ls[0][0][h] + ls[0][1][h] + ls[0][2][h] + ls[0][3][h]);
  } else if (tid < 128) {
    int hh = tid - 64;
    atomicAdd(&stats[64 + hh],
              ls[1][0][hh] + ls[1][1][hh] + ls[1][2][hh] + ls[1][3][hh]);
  }
}

// ---------- x = softplus(BN(o_mean) + x), bf16 x in/out ----------
__global__ __launch_bounds__(256) void k_update(unsigned short* __restrict__ xb,
                                                const float* __restrict__ o,
                                                const float* __restrict__ stats,
                                                const float* __restrict__ g,
                                                const float* __restrict__ b) {
  int t = blockIdx.x * 256 + threadIdx.x;
  int h = t & 63;
  float mean = stats[h] * (1.f / N_NODES);
  float var = stats[64 + h] * (1.f / N_NODES) - mean * mean;
  float is = rsqrtf(var + EPSB);
  float v = (o[t] - mean) * is * g[h] + b[h];
  float r = sp_f(v + bf2f(xb[t]));
  xb[t] = (unsigned short)bfr(r);
}

// ------- graph pooling: chunked register accumulation (batch is sorted) -------
#define PR 512
__global__ __launch_bounds__(256) void k_pool(const unsigned short* __restrict__ xb,
                                              const int* __restrict__ batch,
                                              float* __restrict__ pooled,
                                              float* __restrict__ gcnt) {
  int h = threadIdx.x & 63, rs = threadIdx.x >> 6;
  int r0 = blockIdx.x * PR;
  int rend = min(r0 + PR, N_NODES);
  int gcur = -1;
  float acc = 0.f;
  int cnt = 0;
  for (int r = r0 + rs; r < rend; r += 4) {
    int g = batch[r];
    if (g != gcur) {
      if (gcur >= 0) {
        atomicAdd(&pooled[gcur * 64 + h], acc);
        if (h == 0) atomicAdd(&gcnt[gcur], (float)cnt);
      }
      gcur = g;
      acc = 0.f;
      cnt = 0;
    }
    acc += bf2f(xb[(size_t)r * 64 + h]);
    cnt++;
  }
  if (gcur >= 0) {
    atomicAdd(&pooled[gcur * 64 + h], acc);
    if (h == 0) atomicAdd(&gcnt[gcur], (float)cnt);
  }
}

// -------------------- final dense layers --------------------
__global__ __launch_bounds__(128) void k_final(const float* __restrict__ pooled,
                                               const float* __restrict__ gcnt,
                                               const float* __restrict__ l2w,
                                               const float* __restrict__ l2b,
                                               const float* __restrict__ ow,
                                               const float* __restrict__ ob,
                                               float* __restrict__ out) {
  int g = blockIdx.x;
  int t = threadIdx.x;
  __shared__ float row[64];
  __shared__ float hh[128];
  if (t < 64) row[t] = pooled[g * 64 + t] / fmaxf(gcnt[g], 1.f);
  __syncthreads();
  float acc = l2b[t];
  for (int k = 0; k < 64; ++k) acc += row[k] * l2w[k * 128 + t];
  hh[t] = sp_f(acc) * ow[t];
  __syncthreads();
  for (int s = 64; s > 0; s >>= 1) {
    if (t < s) hh[t] += hh[t + s];
    __syncthreads();
  }
  if (t == 0) out[g] = hh[0] + ob[0];
}

extern "C" void kernel_launch(void* const* d_in, const int* in_sizes, int n_in,
                              void* d_out, int out_size, void* d_ws, size_t ws_size,
                              hipStream_t stream) {
  const float* x_in = (const float*)d_in[0];
  const int* node_idx = (const int*)d_in[1];
  const int* hedge_idx = (const int*)d_in[2];
  const float* hedge_attr = (const float*)d_in[3];
  const int* batch = (const int*)d_in[4];
  const float* embed_w = (const float*)d_in[5];
  const float* embed_b = (const float*)d_in[6];
  const float* f1_w = (const float*)d_in[7];
  const float* c1_w = (const float*)d_in[9];
  const float* f2_w = (const float*)d_in[11];
  const float* f2_b = (const float*)d_in[12];
  const float* c2_w = (const float*)d_in[13];
  const float* c2_b = (const float*)d_in[14];
  const float* bnf_g = (const float*)d_in[15];
  const float* bnf_b = (const float*)d_in[16];
  const float* bnc_g = (const float*)d_in[17];
  const float* bnc_b = (const float*)d_in[18];
  const float* bno_g = (const float*)d_in[19];
  const float* bno_b = (const float*)d_in[20];
  const float* l2_w = (const float*)d_in[21];
  const float* l2_b = (const float*)d_in[22];
  const float* out_w = (const float*)d_in[23];
  const float* out_b = (const float*)d_in[24];

  // workspace layout (bytes, 256-aligned)
  char* base = (char*)d_ws;
  size_t off = 0;
  auto alloc = [&](size_t bytes) {
    size_t o = off;
    off = (off + bytes + 255) & ~(size_t)255;
    return o;
  };
  unsigned short* xbf = (unsigned short*)(base + alloc((size_t)N_NODES * 64 * 2));
  unsigned short* hab = (unsigned short*)(base + alloc((size_t)N_HEDGES * 35 * 2));
  unsigned* Vfc = (unsigned*)(base + alloc((size_t)N_HEDGES * 64 * 4));
  unsigned short* zbuf = (unsigned short*)(base + alloc((size_t)N_HEDGES * 72 * 2));
  float* obuf = (float*)(base + alloc((size_t)N_NODES * 64 * 4));
  unsigned* Ufc = (unsigned*)(base + alloc((size_t)N_NODES * 64 * 4));
  uint4* wpk = (uint4*)(base + alloc((size_t)60 * 64 * 16));
  float* hstatsA = (float*)(base + alloc(3 * 160 * 4));
  float* ostatsA = (float*)(base + alloc(3 * 128 * 4));
  float* pooled = (float*)(base + alloc((size_t)N_GRAPHS * 64 * 4));
  float* gcnt = (float*)(base + alloc((size_t)N_GRAPHS * 4));
  int* degH = (int*)(base + alloc((size_t)N_HEDGES * 4));  // degH|degN adjacent memset
  int* degN = (int*)(base + alloc((size_t)N_NODES * 4));
  int* offH = (int*)(base + alloc((size_t)(N_HEDGES + 1) * 4));  // +1 sentinel
  int* offN = (int*)(base + alloc((size_t)N_NODES * 4));
  float* invdH = (float*)(base + alloc((size_t)N_HEDGES * 4));
  int* bsum = (int*)(base + alloc((size_t)(CHB + CNB) * 4));
  int* rankH = (int*)(base + alloc((size_t)N_INC * 4));
  int* rankN = (int*)(base + alloc((size_t)N_INC * 4));
  int* permHn = (int*)(base + alloc((size_t)N_INC * 4));
  int* permNh = (int*)(base + alloc((size_t)N_INC * 4));
  (void)ws_size;
  (void)in_sizes;
  (void)n_in;
  (void)out_size;

  // ---- ordered CSR build ----
  hipMemsetAsync(degH, 0,
                 (size_t)((char*)degN - (char*)degH) + (size_t)N_NODES * 4, stream);
  k_hist<<<(N_INC + 255) / 256, 256, 0, stream>>>(node_idx, hedge_idx, degN, degH,
                                                  rankN, rankH);
  k_bsum<<<CHB + CNB, 256, 0, stream>>>(degH, degN, bsum);
  k_bscan<<<2, 64, 0, stream>>>(bsum);
  k_alloc2<<<CHB + CNB, 256, 0, stream>>>(degH, degN, bsum, offH, offN, invdH);
  k_fill<<<(N_INC + 255) / 256, 256, 0, stream>>>(node_idx, hedge_idx, rankH, rankN,
                                                  offH, offN, permHn, permNh,
                                                  &offH[N_HEDGES]);
  k_wpack<<<60, 64, 0, stream>>>(f1_w, c1_w, wpk);
  k_cvt_ha<<<(N_HEDGES * 35 + 255) / 256, 256, 0, stream>>>(hedge_attr, hab,
                                                            N_HEDGES * 35);
  k_embed<<<N_NODES / 16, 256, 0, stream>>>(x_in, embed_w, embed_b, xbf);

  // zero all per-layer stats in one go
  hipMemsetAsync(hstatsA, 0, (size_t)((char*)ostatsA - (char*)hstatsA) + 3 * 128 * 4,
                 stream);

  for (int i = 0; i < 3; ++i) {
    float* hstats = hstatsA + i * 160;
    float* ostats = ostatsA + i * 128;

    // fused pipelined gather + MFMA GEMM + stats
    k_hedge_gemm<<<N_HEDGES / GR, 256, 0, stream>>>(
        xbf, permHn, offH, invdH, hab, wpk + (size_t)i * 20 * 64, zbuf, hstats);
    // fused BN+act -> ha + V-projection
    k_hedge_post<<<N_HEDGES / 16, 256, 0, stream>>>(
        zbuf, hstats, bnf_g + i * HE, bnf_b + i * HE, bnc_g + i * HE, bnc_b + i * HE,
        f2_w + i * CAT * 64 + 64 * 64, c2_w + i * CAT * 64 + 64 * 64,
        f2_b + i * 64, c2_b + i * 64, hab, Vfc);

    // node projection
    k_uv_node<<<N_NODES / 16, 256, 0, stream>>>(xbf, f2_w + i * CAT * 64,
                                                c2_w + i * CAT * 64, Ufc);

    // per-node combine + fused BN stats
    k_node_aggr<<<NAGG_GRID, 256, 0, stream>>>(permNh, offN, degN, Ufc, Vfc, obuf,
                                               ostats);

    // node BN + residual softplus
    k_update<<<N_NODES * 64 / 256, 256, 0, stream>>>(xbf, obuf, ostats,
                                                     bno_g + i * 64, bno_b + i * 64);
  }

  // pooling + head
  hipMemsetAsync(pooled, 0, (size_t)((char*)gcnt - (char*)pooled) + N_GRAPHS * 4,
                 stream);
  k_pool<<<(N_NODES + PR - 1) / PR, 256, 0, stream>>>(xbf, batch, pooled, gcnt);
  k_final<<<N_GRAPHS, 128, 0, stream>>>(pooled, gcnt, l2_w, l2_b, out_w, out_b,
                                        (float*)d_out);
}

// Round 12
// 1246.624 us; speedup vs baseline: 1.0413x; 1.0413x over previous
//
#include <hip/hip_runtime.h>
#include <math.h>

#define N_NODES 100000
#define N_HEDGES 200000
#define N_INC 1000000
#define N_GRAPHS 256
#define HD 64
#define HE 35
#define CAT 99
#define EPSB 1e-5f

typedef __attribute__((ext_vector_type(8))) short short8;
typedef __attribute__((ext_vector_type(4))) float f32x4;

__device__ __forceinline__ float sp_f(float x) {
  return fmaxf(x, 0.f) + __logf(1.f + __expf(-fabsf(x)));
}
__device__ __forceinline__ float sig_f(float x) {
  return __builtin_amdgcn_rcpf(1.f + __expf(-x));
}
__device__ __forceinline__ unsigned bfr(float x) {
  unsigned u = __float_as_uint(x);
  return (u + 0x7fffu + ((u >> 16) & 1u)) >> 16;
}
__device__ __forceinline__ unsigned pk2(float lo, float hi) {
  return bfr(lo) | (bfr(hi) << 16);
}
__device__ __forceinline__ float blo(unsigned v) { return __uint_as_float(v << 16); }
__device__ __forceinline__ float bhi(unsigned v) {
  return __uint_as_float(v & 0xffff0000u);
}
__device__ __forceinline__ float bf2f(unsigned short s) {
  return __uint_as_float(((unsigned)s) << 16);
}

// ---- histogram + within-segment ranks ----
__global__ __launch_bounds__(256) void k_hist(const int* __restrict__ nidx,
                                              const int* __restrict__ hidx,
                                              int* __restrict__ degN,
                                              int* __restrict__ degH,
                                              int* __restrict__ rankN,
                                              int* __restrict__ rankH) {
  int e = blockIdx.x * 256 + threadIdx.x;
  if (e >= N_INC) return;
  rankH[e] = atomicAdd(&degH[hidx[e]], 1);
  rankN[e] = atomicAdd(&degN[nidx[e]], 1);
}

#define CHB ((N_HEDGES + 255) / 256)
#define CNB ((N_NODES + 255) / 256)

// ---- per-256-chunk degree sums (both segmentations) ----
__global__ __launch_bounds__(256) void k_bsum(const int* __restrict__ degH,
                                              const int* __restrict__ degN,
                                              int* __restrict__ bsum) {
  __shared__ int s[256];
  int b = blockIdx.x, t = threadIdx.x;
  const int* deg;
  int n, i;
  if (b < CHB) {
    deg = degH; n = N_HEDGES; i = b * 256 + t;
  } else {
    deg = degN; n = N_NODES; i = (b - CHB) * 256 + t;
  }
  s[t] = (i < n) ? deg[i] : 0;
  __syncthreads();
  for (int st = 128; st > 0; st >>= 1) {
    if (t < st) s[t] += s[t + st];
    __syncthreads();
  }
  if (t == 0) bsum[b] = s[0];
}

// ---- exclusive scan of chunk sums, per segment ----
__global__ __launch_bounds__(64) void k_bscan(int* __restrict__ bsum) {
  int seg0 = (blockIdx.x == 0) ? 0 : CHB;
  int segn = (blockIdx.x == 0) ? CHB : CNB;
  int lane = threadIdx.x;
  int carry = 0;
  for (int base = 0; base < segn; base += 64) {
    int i = base + lane;
    int orig = (i < segn) ? bsum[seg0 + i] : 0;
    int v = orig;
    for (int st = 1; st < 64; st <<= 1) {
      int u = __shfl_up(v, st);
      if (lane >= st) v += u;
    }
    int total = __shfl(v, 63);
    if (i < segn) bsum[seg0 + i] = carry + (v - orig);
    carry += total;
  }
}

// ---- ordered CSR offsets (+ reciprocal degrees both sides) ----
__global__ __launch_bounds__(256) void k_alloc2(const int* __restrict__ degH,
                                                const int* __restrict__ degN,
                                                const int* __restrict__ bsum,
                                                int* __restrict__ offH,
                                                int* __restrict__ offN,
                                                float* __restrict__ invdH,
                                                float* __restrict__ invdN) {
  __shared__ int s[256];
  int b = blockIdx.x, t = threadIdx.x;
  const int* deg;
  int* off;
  int n, i;
  bool isH = (b < CHB);
  if (isH) {
    deg = degH; off = offH; n = N_HEDGES; i = b * 256 + t;
  } else {
    deg = degN; off = offN; n = N_NODES; i = (b - CHB) * 256 + t;
  }
  int d = (i < n) ? deg[i] : 0;
  s[t] = d;
  __syncthreads();
  for (int st = 1; st < 256; st <<= 1) {
    int u = 0;
    if (t >= st) u = s[t - st];
    __syncthreads();
    if (t >= st) s[t] += u;
    __syncthreads();
  }
  if (i < n) {
    off[i] = s[t] - d + bsum[b];
    if (isH)
      invdH[i] = 1.f / (float)max(d, 1);
    else
      invdN[i] = 1.f / (float)max(d, 1);
  }
}

// ---- atomic-free CSR fill (+ both sentinels) ----
__global__ __launch_bounds__(256) void k_fill(const int* __restrict__ nidx,
                                              const int* __restrict__ hidx,
                                              const int* __restrict__ rankH,
                                              const int* __restrict__ rankN,
                                              const int* __restrict__ offH,
                                              const int* __restrict__ offN,
                                              int* __restrict__ permHn,
                                              int* __restrict__ permNh,
                                              int* __restrict__ offH_sent,
                                              int* __restrict__ offN_sent) {
  int e = blockIdx.x * 256 + threadIdx.x;
  if (e >= N_INC) return;
  if (e == 0) {
    *offH_sent = N_INC;  // offH[N_HEDGES]
    *offN_sent = N_INC;  // offN[N_NODES]
  }
  int nd = nidx[e], hg = hidx[e];
  permHn[offH[hg] + rankH[e]] = nd;
  permNh[offN[nd] + rankN[e]] = hg;
}

// ---- weight prepack: B[k=0..127][col=0..79] = [Wf | Wc | pad] as MFMA B-frags ----
__global__ __launch_bounds__(64) void k_wpack(const float* __restrict__ f1w,
                                              const float* __restrict__ c1w,
                                              uint4* __restrict__ wpk) {
  int b = blockIdx.x;  // 60 = 3 layers * 5 ct * 4 ks
  int layer = b / 20, rem = b % 20, ct = rem / 4, ks = rem % 4;
  int lane = threadIdx.x;
  int col = ct * 16 + (lane & 15);
  int k0 = ks * 32 + (lane >> 4) * 8;
  const float* wf = f1w + layer * CAT * HE;
  const float* wc = c1w + layer * CAT * HE;
  unsigned v[4];
#pragma unroll
  for (int p = 0; p < 4; ++p) {
    float lo = 0.f, hi = 0.f;
    int ka = k0 + p * 2, kb = ka + 1;
    if (ka < 99) {
      if (col < 35) lo = wf[ka * 35 + col];
      else if (col >= 36 && col < 71) lo = wc[ka * 35 + (col - 36)];
    }
    if (kb < 99) {
      if (col < 35) hi = wf[kb * 35 + col];
      else if (col >= 36 && col < 71) hi = wc[kb * 35 + (col - 36)];
    }
    v[p] = pk2(lo, hi);
  }
  uint4 o;
  o.x = v[0]; o.y = v[1]; o.z = v[2]; o.w = v[3];
  wpk[b * 64 + lane] = o;
}

// ---- hedge_attr f32 -> bf16 once ----
__global__ __launch_bounds__(256) void k_cvt_ha(const float* __restrict__ src,
                                                unsigned short* __restrict__ dst,
                                                int n) {
  int t = blockIdx.x * 256 + threadIdx.x;
  if (t < n) dst[t] = (unsigned short)bfr(src[t]);
}

// -------------------- embed: x[N,92] @ w[92,64] + b -> bf16 --------------------
__global__ __launch_bounds__(256) void k_embed(const float* __restrict__ x,
                                               const float* __restrict__ w,
                                               const float* __restrict__ b,
                                               unsigned short* __restrict__ outb) {
  __shared__ float ws[92 * 64];
  __shared__ float rs[16][93];
  int tid = threadIdx.x;
  for (int i = tid; i < 92 * 64; i += 256) ws[i] = w[i];
  int r0 = blockIdx.x * 16;
  for (int i = tid; i < 16 * 92; i += 256) {
    int r = i / 92, k = i - r * 92;
    rs[r][k] = x[(r0 + r) * 92 + k];
  }
  __syncthreads();
  int h = tid & 63;
  float bias = b[h];
  for (int rr = tid >> 6; rr < 16; rr += 4) {
    float acc = bias;
    for (int k = 0; k < 92; ++k) acc += rs[rr][k] * ws[k * 64 + h];
    outb[(r0 + rr) * 64 + h] = (unsigned short)bfr(acc);
  }
}

// ------ FUSED hedge gather (linear-entry, 8-deep, round-9 proven) + MFMA GEMM ------
#define GR 64
__global__ __launch_bounds__(256) void k_hedge_gemm(
    const unsigned short* __restrict__ xb, const int* __restrict__ permHn,
    const int* __restrict__ offH, const float* __restrict__ invdH,
    const unsigned short* __restrict__ hab, const uint4* __restrict__ wpk,
    unsigned short* __restrict__ z, float* __restrict__ stats) {
  __shared__ unsigned short msg[GR * 128];
  __shared__ float ps[160];
  __shared__ int bndL[4][18];
  int tid = threadIdx.x;
  int w = tid >> 6, lane = tid & 63;
  int r0 = blockIdx.x * GR;
  if (tid < 160) ps[tid] = 0.f;

  // B-fragments (L2-resident)
  short8 bfg[5][4];
#pragma unroll
  for (int ct = 0; ct < 5; ++ct)
#pragma unroll
    for (int ks = 0; ks < 4; ++ks)
      bfg[ct][ks] = __builtin_bit_cast(short8, wpk[(ct * 4 + ks) * 64 + lane]);

  char* mb = (char*)msg;
  // cooperative hab staging into msg cols 64..127 (zero-padded past 98)
  for (int i = tid; i < GR * 64; i += 256) {
    int r = i >> 6, c = 64 + (i & 63);
    unsigned short hv = 0;
    if (c < 99) hv = hab[(size_t)(r0 + r) * 35 + (c - 64)];
    *(unsigned short*)(mb + ((r * 256 + c * 2) ^ ((r & 7) << 4))) = hv;
  }

  // per-wave row bounds (17 values; offH has sentinel at N_HEDGES)
  int r0w = r0 + w * 16;
  if (lane < 17) bndL[w][lane] = offH[r0w + lane];
  int eBeg = bndL[w][0], eEnd = bndL[w][16];

  int j = 0;
  int nb = bndL[w][1];
  float acc = 0.f;
  for (int chunk = eBeg; chunk < eEnd; chunk += 8) {
    float v[8];
#pragma unroll
    for (int t = 0; t < 8; ++t) {
      int idx = permHn[min(chunk + t, eEnd - 1)];
      v[t] = bf2f(xb[(size_t)idx * 64 + lane]);  // unconditional, 8-deep cluster
    }
#pragma unroll
    for (int t = 0; t < 8; ++t) {
      int e = chunk + t;
      if (e >= eEnd) break;
      while (e >= nb) {  // flush completed row j (wave-uniform)
        int rl = w * 16 + j;
        unsigned short mv = (unsigned short)bfr(acc * invdH[r0w + j]);
        *(unsigned short*)(mb + ((rl * 256 + lane * 2) ^ ((rl & 7) << 4))) = mv;
        acc = 0.f;
        ++j;
        nb = bndL[w][j + 1];
      }
      acc += v[t];
    }
  }
  for (; j < 16; ++j) {  // tail flush (incl. empty rows)
    int rl = w * 16 + j;
    unsigned short mv = (unsigned short)bfr(acc * invdH[r0w + j]);
    *(unsigned short*)(mb + ((rl * 256 + lane * 2) ^ ((rl & 7) << 4))) = mv;
    acc = 0.f;
  }
  __syncthreads();

  // MFMA + stats + bf16 Z write (one 16-row tile per wave)
  {
    int rloc = w * 16 + (lane & 15);
    short8 a[4];
#pragma unroll
    for (int ks = 0; ks < 4; ++ks) {
      int byte = rloc * 256 + (ks * 32 + (lane >> 4) * 8) * 2;
      a[ks] = *(const short8*)(mb + (byte ^ ((rloc & 7) << 4)));
    }
#pragma unroll
    for (int ct = 0; ct < 5; ++ct) {
      f32x4 acc4 = {0.f, 0.f, 0.f, 0.f};
#pragma unroll
      for (int ks = 0; ks < 4; ++ks)
        acc4 = __builtin_amdgcn_mfma_f32_16x16x32_bf16(a[ks], bfg[ct][ks], acc4, 0, 0, 0);
      float s = (acc4[0] + acc4[1]) + (acc4[2] + acc4[3]);
      float q = (acc4[0] * acc4[0] + acc4[1] * acc4[1]) +
                (acc4[2] * acc4[2] + acc4[3] * acc4[3]);
      s += __shfl_xor(s, 16);
      s += __shfl_xor(s, 32);
      q += __shfl_xor(q, 16);
      q += __shfl_xor(q, 32);
      int col = ct * 16 + (lane & 15);
      if ((lane >> 4) == 0 && col < 72) {
        atomicAdd(&ps[col], s);
        atomicAdd(&ps[80 + col], q);
      }
      int growb = r0 + w * 16 + ((lane >> 4) << 2);
      if (col < 72) {
#pragma unroll
        for (int r = 0; r < 4; ++r)
          z[(size_t)(growb + r) * 72 + col] = (unsigned short)bfr(acc4[r]);
      }
    }
  }
  __syncthreads();
  if (tid < 160) atomicAdd(&stats[tid], ps[tid]);
}

// ---- FUSED: BN+act over Z -> ha (bf16, global) AND V = ha @ W2b + bias -> Vfc ----
__global__ __launch_bounds__(256) void k_hedge_post(
    const unsigned short* __restrict__ z, const float* __restrict__ stats,
    const float* __restrict__ gf, const float* __restrict__ bf_,
    const float* __restrict__ gc, const float* __restrict__ bc_,
    const float* __restrict__ f2wb, const float* __restrict__ c2wb,
    const float* __restrict__ f2b, const float* __restrict__ c2b,
    unsigned short* __restrict__ hab, unsigned* __restrict__ Vfc) {
  __shared__ float wf[35 * 64];
  __shared__ float wc[35 * 64];
  __shared__ float rs[16][36];
  __shared__ float sf[4][35];  // scaleF, shiftF, scaleC, shiftC
  int tid = threadIdx.x;
  for (int i = tid; i < 35 * 64; i += 256) {
    wf[i] = f2wb[i];
    wc[i] = c2wb[i];
  }
  if (tid < 35) {
    const float inv = 1.f / N_HEDGES;
    float mf = stats[tid] * inv;
    float vf = stats[80 + tid] * inv - mf * mf;
    float mc = stats[36 + tid] * inv;
    float vc = stats[116 + tid] * inv - mc * mc;
    float a = rsqrtf(vf + EPSB) * gf[tid];
    float b = rsqrtf(vc + EPSB) * gc[tid];
    sf[0][tid] = a;
    sf[1][tid] = bf_[tid] - mf * a;
    sf[2][tid] = b;
    sf[3][tid] = bc_[tid] - mc * b;
  }
  __syncthreads();
  int r0 = blockIdx.x * 16;
  for (int i = tid; i < 16 * 35; i += 256) {
    int r = i / 35, c = i - r * 35;
    const unsigned short* zr = &z[(size_t)(r0 + r) * 72];
    float nf = bf2f(zr[c]) * sf[0][c] + sf[1][c];
    float nc = bf2f(zr[36 + c]) * sf[2][c] + sf[3][c];
    float ha = sig_f(nf) * sp_f(nc);
    rs[r][c] = ha;
    hab[(size_t)(r0 + r) * 35 + c] = (unsigned short)bfr(ha);
  }
  __syncthreads();
  int h = tid & 63, rb = tid >> 6;
  float af0, af1, af2, af3, ac0, ac1, ac2, ac3;
  af0 = af1 = af2 = af3 = f2b[h];
  ac0 = ac1 = ac2 = ac3 = c2b[h];
  for (int k = 0; k < 35; ++k) {
    float wfv = wf[k * 64 + h], wcv = wc[k * 64 + h];
    float m0 = rs[rb][k], m1 = rs[rb + 4][k], m2 = rs[rb + 8][k], m3 = rs[rb + 12][k];
    af0 += m0 * wfv; ac0 += m0 * wcv;
    af1 += m1 * wfv; ac1 += m1 * wcv;
    af2 += m2 * wfv; ac2 += m2 * wcv;
    af3 += m3 * wfv; ac3 += m3 * wcv;
  }
  int row = r0 + rb;
  Vfc[row * 64 + h] = pk2(af0, ac0);
  Vfc[(row + 4) * 64 + h] = pk2(af1, ac1);
  Vfc[(row + 8) * 64 + h] = pk2(af2, ac2);
  Vfc[(row + 12) * 64 + h] = pk2(af3, ac3);
}

// ---- per-node projection: U = x @ W[0:64,:], bf16 in, packed bf16x2 out ----
__global__ __launch_bounds__(256) void k_uv_node(const unsigned short* __restrict__ xb,
                                                 const float* __restrict__ f2w,
                                                 const float* __restrict__ c2w,
                                                 unsigned* __restrict__ Ufc) {
  __shared__ float wf[64 * 64];
  __shared__ float wc[64 * 64];
  __shared__ float rs[16][65];
  int tid = threadIdx.x;
  for (int i = tid; i < 64 * 64; i += 256) {
    wf[i] = f2w[i];
    wc[i] = c2w[i];
  }
  int r0 = blockIdx.x * 16;
  for (int i = tid; i < 16 * 64; i += 256) {
    int r = i >> 6, k = i & 63;
    rs[r][k] = bf2f(xb[(size_t)(r0 + r) * 64 + k]);
  }
  __syncthreads();
  int h = tid & 63, rb = tid >> 6;
  float af0 = 0, af1 = 0, af2 = 0, af3 = 0, ac0 = 0, ac1 = 0, ac2 = 0, ac3 = 0;
  for (int k = 0; k < 64; ++k) {
    float wfv = wf[k * 64 + h], wcv = wc[k * 64 + h];
    float m0 = rs[rb][k], m1 = rs[rb + 4][k], m2 = rs[rb + 8][k], m3 = rs[rb + 12][k];
    af0 += m0 * wfv; ac0 += m0 * wcv;
    af1 += m1 * wfv; ac1 += m1 * wcv;
    af2 += m2 * wfv; ac2 += m2 * wcv;
    af3 += m3 * wfv; ac3 += m3 * wcv;
  }
  int row = r0 + rb;
  Ufc[row * 64 + h] = pk2(af0, ac0);
  Ufc[(row + 4) * 64 + h] = pk2(af1, ac1);
  Ufc[(row + 8) * 64 + h] = pk2(af2, ac2);
  Ufc[(row + 12) * 64 + h] = pk2(af3, ac3);
}

// ------ per-node aggregate: linear-entry 8-deep chunked walk + fused BN stats ------
__device__ __forceinline__ float act2(float uf, float uc, unsigned v) {
  float a = uf + blo(v);
  float b = uc + bhi(v);
  return sig_f(a) * sp_f(b);
}
// 4 waves x 16 nodes = 64 nodes/block; wave's perm range is contiguous (ordered CSR).
__global__ __launch_bounds__(256) void k_node_aggr(const int* __restrict__ permNh,
                                                   const int* __restrict__ offN,
                                                   const float* __restrict__ invdN,
                                                   const unsigned* __restrict__ Ufc,
                                                   const unsigned* __restrict__ Vfc,
                                                   float* __restrict__ o,
                                                   float* __restrict__ stats) {
  __shared__ int bndL[4][18];
  __shared__ float ls[2][4][64];
  int tid = threadIdx.x;
  int w = tid >> 6, lane = tid & 63;  // lane = feature h
  int r0w = blockIdx.x * 64 + w * 16;
  if (lane < 17) bndL[w][lane] = offN[min(r0w + lane, N_NODES)];
  int eBeg = bndL[w][0], eEnd = bndL[w][16];

  int j = 0;
  int nb = bndL[w][1];
  float acc = 0.f, sacc = 0.f, qacc = 0.f;
  unsigned u0 = (r0w < N_NODES) ? Ufc[(size_t)r0w * 64 + lane] : 0u;
  float uf = blo(u0), uc = bhi(u0);

  for (int chunk = eBeg; chunk < eEnd; chunk += 8) {
    unsigned pv[8];
#pragma unroll
    for (int t = 0; t < 8; ++t) {
      int hg = permNh[min(chunk + t, eEnd - 1)];
      pv[t] = Vfc[(size_t)hg * 64 + lane];  // unconditional, 8 rows in flight
    }
#pragma unroll
    for (int t = 0; t < 8; ++t) {
      int e = chunk + t;
      if (e >= eEnd) break;
      while (e >= nb) {  // flush completed node j (wave-uniform)
        int row = r0w + j;
        float val = acc * invdN[row];
        o[(size_t)row * 64 + lane] = val;
        sacc += val;
        qacc += val * val;
        acc = 0.f;
        ++j;
        nb = bndL[w][j + 1];
        unsigned un = Ufc[(size_t)(r0w + j) * 64 + lane];
        uf = blo(un);
        uc = bhi(un);
      }
      acc += act2(uf, uc, pv[t]);
    }
  }
  for (; j < 16; ++j) {  // tail flush (incl. empty nodes)
    int row = r0w + j;
    if (row < N_NODES) {
      float val = acc * invdN[row];
      o[(size_t)row * 64 + lane] = val;
      sacc += val;
      qacc += val * val;
    }
    acc = 0.f;
  }

  ls[0][w][lane] = sacc;
  ls[1][w][lane] = qacc;
  __syncthreads();
  if (tid < 64) {
    atomicAdd(&stats[lane],
              ls[0][0][lane] + ls[0][1][lane] + ls[0][2][lane] + ls[0][3][lane]);
  } else if (tid < 128) {
    int hh = tid - 64;
    atomicAdd(&stats[64 + hh],
              ls[1][0][hh] + ls[1][1][hh] + ls[1][2][hh] + ls[1][3][hh]);
  }
}

// ---------- x = softplus(BN(o_mean) + x), bf16 x in/out ----------
__global__ __launch_bounds__(256) void k_update(unsigned short* __restrict__ xb,
                                                const float* __restrict__ o,
                                                const float* __restrict__ stats,
                                                const float* __restrict__ g,
                                                const float* __restrict__ b) {
  int t = blockIdx.x * 256 + threadIdx.x;
  int h = t & 63;
  float mean = stats[h] * (1.f / N_NODES);
  float var = stats[64 + h] * (1.f / N_NODES) - mean * mean;
  float is = rsqrtf(var + EPSB);
  float v = (o[t] - mean) * is * g[h] + b[h];
  float r = sp_f(v + bf2f(xb[t]));
  xb[t] = (unsigned short)bfr(r);
}

// ------- graph pooling: chunked register accumulation (batch is sorted) -------
#define PR 512
__global__ __launch_bounds__(256) void k_pool(const unsigned short* __restrict__ xb,
                                              const int* __restrict__ batch,
                                              float* __restrict__ pooled,
                                              float* __restrict__ gcnt) {
  int h = threadIdx.x & 63, rs = threadIdx.x >> 6;
  int r0 = blockIdx.x * PR;
  int rend = min(r0 + PR, N_NODES);
  int gcur = -1;
  float acc = 0.f;
  int cnt = 0;
  for (int r = r0 + rs; r < rend; r += 4) {
    int g = batch[r];
    if (g != gcur) {
      if (gcur >= 0) {
        atomicAdd(&pooled[gcur * 64 + h], acc);
        if (h == 0) atomicAdd(&gcnt[gcur], (float)cnt);
      }
      gcur = g;
      acc = 0.f;
      cnt = 0;
    }
    acc += bf2f(xb[(size_t)r * 64 + h]);
    cnt++;
  }
  if (gcur >= 0) {
    atomicAdd(&pooled[gcur * 64 + h], acc);
    if (h == 0) atomicAdd(&gcnt[gcur], (float)cnt);
  }
}

// -------------------- final dense layers --------------------
__global__ __launch_bounds__(128) void k_final(const float* __restrict__ pooled,
                                               const float* __restrict__ gcnt,
                                               const float* __restrict__ l2w,
                                               const float* __restrict__ l2b,
                                               const float* __restrict__ ow,
                                               const float* __restrict__ ob,
                                               float* __restrict__ out) {
  int g = blockIdx.x;
  int t = threadIdx.x;
  __shared__ float row[64];
  __shared__ float hh[128];
  if (t < 64) row[t] = pooled[g * 64 + t] / fmaxf(gcnt[g], 1.f);
  __syncthreads();
  float acc = l2b[t];
  for (int k = 0; k < 64; ++k) acc += row[k] * l2w[k * 128 + t];
  hh[t] = sp_f(acc) * ow[t];
  __syncthreads();
  for (int s = 64; s > 0; s >>= 1) {
    if (t < s) hh[t] += hh[t + s];
    __syncthreads();
  }
  if (t == 0) out[g] = hh[0] + ob[0];
}

extern "C" void kernel_launch(void* const* d_in, const int* in_sizes, int n_in,
                              void* d_out, int out_size, void* d_ws, size_t ws_size,
                              hipStream_t stream) {
  const float* x_in = (const float*)d_in[0];
  const int* node_idx = (const int*)d_in[1];
  const int* hedge_idx = (const int*)d_in[2];
  const float* hedge_attr = (const float*)d_in[3];
  const int* batch = (const int*)d_in[4];
  const float* embed_w = (const float*)d_in[5];
  const float* embed_b = (const float*)d_in[6];
  const float* f1_w = (const float*)d_in[7];
  const float* c1_w = (const float*)d_in[9];
  const float* f2_w = (const float*)d_in[11];
  const float* f2_b = (const float*)d_in[12];
  const float* c2_w = (const float*)d_in[13];
  const float* c2_b = (const float*)d_in[14];
  const float* bnf_g = (const float*)d_in[15];
  const float* bnf_b = (const float*)d_in[16];
  const float* bnc_g = (const float*)d_in[17];
  const float* bnc_b = (const float*)d_in[18];
  const float* bno_g = (const float*)d_in[19];
  const float* bno_b = (const float*)d_in[20];
  const float* l2_w = (const float*)d_in[21];
  const float* l2_b = (const float*)d_in[22];
  const float* out_w = (const float*)d_in[23];
  const float* out_b = (const float*)d_in[24];

  // workspace layout (bytes, 256-aligned)
  char* base = (char*)d_ws;
  size_t off = 0;
  auto alloc = [&](size_t bytes) {
    size_t o = off;
    off = (off + bytes + 255) & ~(size_t)255;
    return o;
  };
  unsigned short* xbf = (unsigned short*)(base + alloc((size_t)N_NODES * 64 * 2));
  unsigned short* hab = (unsigned short*)(base + alloc((size_t)N_HEDGES * 35 * 2));
  unsigned* Vfc = (unsigned*)(base + alloc((size_t)N_HEDGES * 64 * 4));
  unsigned short* zbuf = (unsigned short*)(base + alloc((size_t)N_HEDGES * 72 * 2));
  float* obuf = (float*)(base + alloc((size_t)N_NODES * 64 * 4));
  unsigned* Ufc = (unsigned*)(base + alloc((size_t)N_NODES * 64 * 4));
  uint4* wpk = (uint4*)(base + alloc((size_t)60 * 64 * 16));
  float* hstatsA = (float*)(base + alloc(3 * 160 * 4));
  float* ostatsA = (float*)(base + alloc(3 * 128 * 4));
  float* pooled = (float*)(base + alloc((size_t)N_GRAPHS * 64 * 4));
  float* gcnt = (float*)(base + alloc((size_t)N_GRAPHS * 4));
  int* degH = (int*)(base + alloc((size_t)N_HEDGES * 4));  // degH|degN adjacent memset
  int* degN = (int*)(base + alloc((size_t)N_NODES * 4));
  int* offH = (int*)(base + alloc((size_t)(N_HEDGES + 1) * 4));  // +1 sentinel
  int* offN = (int*)(base + alloc((size_t)(N_NODES + 1) * 4));   // +1 sentinel
  float* invdH = (float*)(base + alloc((size_t)N_HEDGES * 4));
  float* invdN = (float*)(base + alloc((size_t)N_NODES * 4));
  int* bsum = (int*)(base + alloc((size_t)(CHB + CNB) * 4));
  int* rankH = (int*)(base + alloc((size_t)N_INC * 4));
  int* rankN = (int*)(base + alloc((size_t)N_INC * 4));
  int* permHn = (int*)(base + alloc((size_t)N_INC * 4));
  int* permNh = (int*)(base + alloc((size_t)N_INC * 4));
  (void)ws_size;
  (void)in_sizes;
  (void)n_in;
  (void)out_size;

  // ---- ordered CSR build ----
  hipMemsetAsync(degH, 0,
                 (size_t)((char*)degN - (char*)degH) + (size_t)N_NODES * 4, stream);
  k_hist<<<(N_INC + 255) / 256, 256, 0, stream>>>(node_idx, hedge_idx, degN, degH,
                                                  rankN, rankH);
  k_bsum<<<CHB + CNB, 256, 0, stream>>>(degH, degN, bsum);
  k_bscan<<<2, 64, 0, stream>>>(bsum);
  k_alloc2<<<CHB + CNB, 256, 0, stream>>>(degH, degN, bsum, offH, offN, invdH, invdN);
  k_fill<<<(N_INC + 255) / 256, 256, 0, stream>>>(node_idx, hedge_idx, rankH, rankN,
                                                  offH, offN, permHn, permNh,
                                                  &offH[N_HEDGES], &offN[N_NODES]);
  k_wpack<<<60, 64, 0, stream>>>(f1_w, c1_w, wpk);
  k_cvt_ha<<<(N_HEDGES * 35 + 255) / 256, 256, 0, stream>>>(hedge_attr, hab,
                                                            N_HEDGES * 35);
  k_embed<<<N_NODES / 16, 256, 0, stream>>>(x_in, embed_w, embed_b, xbf);

  // zero all per-layer stats in one go
  hipMemsetAsync(hstatsA, 0, (size_t)((char*)ostatsA - (char*)hstatsA) + 3 * 128 * 4,
                 stream);

  for (int i = 0; i < 3; ++i) {
    float* hstats = hstatsA + i * 160;
    float* ostats = ostatsA + i * 128;

    // fused pipelined gather + MFMA GEMM + stats
    k_hedge_gemm<<<N_HEDGES / GR, 256, 0, stream>>>(
        xbf, permHn, offH, invdH, hab, wpk + (size_t)i * 20 * 64, zbuf, hstats);
    // fused BN+act -> ha + V-projection
    k_hedge_post<<<N_HEDGES / 16, 256, 0, stream>>>(
        zbuf, hstats, bnf_g + i * HE, bnf_b + i * HE, bnc_g + i * HE, bnc_b + i * HE,
        f2_w + i * CAT * 64 + 64 * 64, c2_w + i * CAT * 64 + 64 * 64,
        f2_b + i * 64, c2_b + i * 64, hab, Vfc);

    // node projection
    k_uv_node<<<N_NODES / 16, 256, 0, stream>>>(xbf, f2_w + i * CAT * 64,
                                                c2_w + i * CAT * 64, Ufc);

    // per-node combine (linear-entry chunked walk) + fused BN stats
    k_node_aggr<<<(N_NODES + 63) / 64, 256, 0, stream>>>(permNh, offN, invdN, Ufc,
                                                         Vfc, obuf, ostats);

    // node BN + residual softplus
    k_update<<<N_NODES * 64 / 256, 256, 0, stream>>>(xbf, obuf, ostats,
                                                     bno_g + i * 64, bno_b + i * 64);
  }

  // pooling + head
  hipMemsetAsync(pooled, 0, (size_t)((char*)gcnt - (char*)pooled) + N_GRAPHS * 4,
                 stream);
  k_pool<<<(N_NODES + PR - 1) / PR, 256, 0, stream>>>(xbf, batch, pooled, gcnt);
  k_final<<<N_GRAPHS, 128, 0, stream>>>(pooled, gcnt, l2_w, l2_b, out_w, out_b,
                                        (float*)d_out);
}

// Round 13
// 1233.641 us; speedup vs baseline: 1.0522x; 1.0105x over previous
//
#include <hip/hip_runtime.h>
#include <math.h>

#define N_NODES 100000
#define N_HEDGES 200000
#define N_INC 1000000
#define N_GRAPHS 256
#define HD 64
#define HE 35
#define CAT 99
#define EPSB 1e-5f

typedef __attribute__((ext_vector_type(8))) short short8;
typedef __attribute__((ext_vector_type(4))) float f32x4;

__device__ __forceinline__ float sp_f(float x) {
  return fmaxf(x, 0.f) + __logf(1.f + __expf(-fabsf(x)));
}
__device__ __forceinline__ float sig_f(float x) {
  return __builtin_amdgcn_rcpf(1.f + __expf(-x));
}
__device__ __forceinline__ unsigned bfr(float x) {
  unsigned u = __float_as_uint(x);
  return (u + 0x7fffu + ((u >> 16) & 1u)) >> 16;
}
__device__ __forceinline__ unsigned pk2(float lo, float hi) {
  return bfr(lo) | (bfr(hi) << 16);
}
__device__ __forceinline__ float blo(unsigned v) { return __uint_as_float(v << 16); }
__device__ __forceinline__ float bhi(unsigned v) {
  return __uint_as_float(v & 0xffff0000u);
}
__device__ __forceinline__ float bf2f(unsigned short s) {
  return __uint_as_float(((unsigned)s) << 16);
}

// ---- histogram + within-segment ranks ----
__global__ __launch_bounds__(256) void k_hist(const int* __restrict__ nidx,
                                              const int* __restrict__ hidx,
                                              int* __restrict__ degN,
                                              int* __restrict__ degH,
                                              int* __restrict__ rankN,
                                              int* __restrict__ rankH) {
  int e = blockIdx.x * 256 + threadIdx.x;
  if (e >= N_INC) return;
  rankH[e] = atomicAdd(&degH[hidx[e]], 1);
  rankN[e] = atomicAdd(&degN[nidx[e]], 1);
}

#define CHB ((N_HEDGES + 255) / 256)
#define CNB ((N_NODES + 255) / 256)

// ---- per-256-chunk degree sums (both segmentations) ----
__global__ __launch_bounds__(256) void k_bsum(const int* __restrict__ degH,
                                              const int* __restrict__ degN,
                                              int* __restrict__ bsum) {
  __shared__ int s[256];
  int b = blockIdx.x, t = threadIdx.x;
  const int* deg;
  int n, i;
  if (b < CHB) {
    deg = degH; n = N_HEDGES; i = b * 256 + t;
  } else {
    deg = degN; n = N_NODES; i = (b - CHB) * 256 + t;
  }
  s[t] = (i < n) ? deg[i] : 0;
  __syncthreads();
  for (int st = 128; st > 0; st >>= 1) {
    if (t < st) s[t] += s[t + st];
    __syncthreads();
  }
  if (t == 0) bsum[b] = s[0];
}

// ---- exclusive scan of chunk sums, per segment ----
__global__ __launch_bounds__(64) void k_bscan(int* __restrict__ bsum) {
  int seg0 = (blockIdx.x == 0) ? 0 : CHB;
  int segn = (blockIdx.x == 0) ? CHB : CNB;
  int lane = threadIdx.x;
  int carry = 0;
  for (int base = 0; base < segn; base += 64) {
    int i = base + lane;
    int orig = (i < segn) ? bsum[seg0 + i] : 0;
    int v = orig;
    for (int st = 1; st < 64; st <<= 1) {
      int u = __shfl_up(v, st);
      if (lane >= st) v += u;
    }
    int total = __shfl(v, 63);
    if (i < segn) bsum[seg0 + i] = carry + (v - orig);
    carry += total;
  }
}

// ---- ordered CSR offsets (+ reciprocal degrees both sides) ----
__global__ __launch_bounds__(256) void k_alloc2(const int* __restrict__ degH,
                                                const int* __restrict__ degN,
                                                const int* __restrict__ bsum,
                                                int* __restrict__ offH,
                                                int* __restrict__ offN,
                                                float* __restrict__ invdH,
                                                float* __restrict__ invdN) {
  __shared__ int s[256];
  int b = blockIdx.x, t = threadIdx.x;
  const int* deg;
  int* off;
  int n, i;
  bool isH = (b < CHB);
  if (isH) {
    deg = degH; off = offH; n = N_HEDGES; i = b * 256 + t;
  } else {
    deg = degN; off = offN; n = N_NODES; i = (b - CHB) * 256 + t;
  }
  int d = (i < n) ? deg[i] : 0;
  s[t] = d;
  __syncthreads();
  for (int st = 1; st < 256; st <<= 1) {
    int u = 0;
    if (t >= st) u = s[t - st];
    __syncthreads();
    if (t >= st) s[t] += u;
    __syncthreads();
  }
  if (i < n) {
    off[i] = s[t] - d + bsum[b];
    if (isH)
      invdH[i] = 1.f / (float)max(d, 1);
    else
      invdN[i] = 1.f / (float)max(d, 1);
  }
}

// ---- atomic-free CSR fill (+ both sentinels) ----
__global__ __launch_bounds__(256) void k_fill(const int* __restrict__ nidx,
                                              const int* __restrict__ hidx,
                                              const int* __restrict__ rankH,
                                              const int* __restrict__ rankN,
                                              const int* __restrict__ offH,
                                              const int* __restrict__ offN,
                                              int* __restrict__ permHn,
                                              int* __restrict__ permNh,
                                              int* __restrict__ offH_sent,
                                              int* __restrict__ offN_sent) {
  int e = blockIdx.x * 256 + threadIdx.x;
  if (e >= N_INC) return;
  if (e == 0) {
    *offH_sent = N_INC;  // offH[N_HEDGES]
    *offN_sent = N_INC;  // offN[N_NODES]
  }
  int nd = nidx[e], hg = hidx[e];
  permHn[offH[hg] + rankH[e]] = nd;
  permNh[offN[nd] + rankN[e]] = hg;
}

// ---- weight prepack: B[k=0..127][col=0..79] = [Wf | Wc | pad] as MFMA B-frags ----
__global__ __launch_bounds__(64) void k_wpack(const float* __restrict__ f1w,
                                              const float* __restrict__ c1w,
                                              uint4* __restrict__ wpk) {
  int b = blockIdx.x;  // 60 = 3 layers * 5 ct * 4 ks
  int layer = b / 20, rem = b % 20, ct = rem / 4, ks = rem % 4;
  int lane = threadIdx.x;
  int col = ct * 16 + (lane & 15);
  int k0 = ks * 32 + (lane >> 4) * 8;
  const float* wf = f1w + layer * CAT * HE;
  const float* wc = c1w + layer * CAT * HE;
  unsigned v[4];
#pragma unroll
  for (int p = 0; p < 4; ++p) {
    float lo = 0.f, hi = 0.f;
    int ka = k0 + p * 2, kb = ka + 1;
    if (ka < 99) {
      if (col < 35) lo = wf[ka * 35 + col];
      else if (col >= 36 && col < 71) lo = wc[ka * 35 + (col - 36)];
    }
    if (kb < 99) {
      if (col < 35) hi = wf[kb * 35 + col];
      else if (col >= 36 && col < 71) hi = wc[kb * 35 + (col - 36)];
    }
    v[p] = pk2(lo, hi);
  }
  uint4 o;
  o.x = v[0]; o.y = v[1]; o.z = v[2]; o.w = v[3];
  wpk[b * 64 + lane] = o;
}

// ---- hedge_attr f32 -> bf16 once ----
__global__ __launch_bounds__(256) void k_cvt_ha(const float* __restrict__ src,
                                                unsigned short* __restrict__ dst,
                                                int n) {
  int t = blockIdx.x * 256 + threadIdx.x;
  if (t < n) dst[t] = (unsigned short)bfr(src[t]);
}

// -------------------- embed: x[N,92] @ w[92,64] + b -> bf16 --------------------
__global__ __launch_bounds__(256) void k_embed(const float* __restrict__ x,
                                               const float* __restrict__ w,
                                               const float* __restrict__ b,
                                               unsigned short* __restrict__ outb) {
  __shared__ float ws[92 * 64];
  __shared__ float rs[16][93];
  int tid = threadIdx.x;
  for (int i = tid; i < 92 * 64; i += 256) ws[i] = w[i];
  int r0 = blockIdx.x * 16;
  for (int i = tid; i < 16 * 92; i += 256) {
    int r = i / 92, k = i - r * 92;
    rs[r][k] = x[(r0 + r) * 92 + k];
  }
  __syncthreads();
  int h = tid & 63;
  float bias = b[h];
  for (int rr = tid >> 6; rr < 16; rr += 4) {
    float acc = bias;
    for (int k = 0; k < 92; ++k) acc += rs[rr][k] * ws[k * 64 + h];
    outb[(r0 + rr) * 64 + h] = (unsigned short)bfr(acc);
  }
}

// ------ FUSED hedge gather (linear-entry, 16-deep) + MFMA GEMM ------
#define GR 64
__global__ __launch_bounds__(256) void k_hedge_gemm(
    const unsigned short* __restrict__ xb, const int* __restrict__ permHn,
    const int* __restrict__ offH, const float* __restrict__ invdH,
    const unsigned short* __restrict__ hab, const uint4* __restrict__ wpk,
    unsigned short* __restrict__ z, float* __restrict__ stats) {
  __shared__ unsigned short msg[GR * 128];
  __shared__ float ps[160];
  __shared__ int bndL[4][18];
  int tid = threadIdx.x;
  int w = tid >> 6, lane = tid & 63;
  int r0 = blockIdx.x * GR;
  if (tid < 160) ps[tid] = 0.f;

  // B-fragments (L2-resident)
  short8 bfg[5][4];
#pragma unroll
  for (int ct = 0; ct < 5; ++ct)
#pragma unroll
    for (int ks = 0; ks < 4; ++ks)
      bfg[ct][ks] = __builtin_bit_cast(short8, wpk[(ct * 4 + ks) * 64 + lane]);

  char* mb = (char*)msg;
  // cooperative hab staging into msg cols 64..127 (zero-padded past 98)
  for (int i = tid; i < GR * 64; i += 256) {
    int r = i >> 6, c = 64 + (i & 63);
    unsigned short hv = 0;
    if (c < 99) hv = hab[(size_t)(r0 + r) * 35 + (c - 64)];
    *(unsigned short*)(mb + ((r * 256 + c * 2) ^ ((r & 7) << 4))) = hv;
  }

  // per-wave row bounds (17 values; offH has sentinel at N_HEDGES)
  int r0w = r0 + w * 16;
  if (lane < 17) bndL[w][lane] = offH[r0w + lane];
  int eBeg = bndL[w][0], eEnd = bndL[w][16];

  int j = 0;
  int nb = bndL[w][1];
  float acc = 0.f;
  for (int chunk = eBeg; chunk < eEnd; chunk += 16) {
    float v[16];
#pragma unroll
    for (int t = 0; t < 16; ++t) {
      int idx = permHn[min(chunk + t, eEnd - 1)];
      v[t] = bf2f(xb[(size_t)idx * 64 + lane]);  // unconditional, 16-deep cluster
    }
#pragma unroll
    for (int t = 0; t < 16; ++t) {
      int e = chunk + t;
      if (e >= eEnd) break;
      while (e >= nb) {  // flush completed row j (wave-uniform)
        int rl = w * 16 + j;
        unsigned short mv = (unsigned short)bfr(acc * invdH[r0w + j]);
        *(unsigned short*)(mb + ((rl * 256 + lane * 2) ^ ((rl & 7) << 4))) = mv;
        acc = 0.f;
        ++j;
        nb = bndL[w][j + 1];
      }
      acc += v[t];
    }
  }
  for (; j < 16; ++j) {  // tail flush (incl. empty rows)
    int rl = w * 16 + j;
    unsigned short mv = (unsigned short)bfr(acc * invdH[r0w + j]);
    *(unsigned short*)(mb + ((rl * 256 + lane * 2) ^ ((rl & 7) << 4))) = mv;
    acc = 0.f;
  }
  __syncthreads();

  // MFMA + stats + bf16 Z write (one 16-row tile per wave)
  {
    int rloc = w * 16 + (lane & 15);
    short8 a[4];
#pragma unroll
    for (int ks = 0; ks < 4; ++ks) {
      int byte = rloc * 256 + (ks * 32 + (lane >> 4) * 8) * 2;
      a[ks] = *(const short8*)(mb + (byte ^ ((rloc & 7) << 4)));
    }
#pragma unroll
    for (int ct = 0; ct < 5; ++ct) {
      f32x4 acc4 = {0.f, 0.f, 0.f, 0.f};
#pragma unroll
      for (int ks = 0; ks < 4; ++ks)
        acc4 = __builtin_amdgcn_mfma_f32_16x16x32_bf16(a[ks], bfg[ct][ks], acc4, 0, 0, 0);
      float s = (acc4[0] + acc4[1]) + (acc4[2] + acc4[3]);
      float q = (acc4[0] * acc4[0] + acc4[1] * acc4[1]) +
                (acc4[2] * acc4[2] + acc4[3] * acc4[3]);
      s += __shfl_xor(s, 16);
      s += __shfl_xor(s, 32);
      q += __shfl_xor(q, 16);
      q += __shfl_xor(q, 32);
      int col = ct * 16 + (lane & 15);
      if ((lane >> 4) == 0 && col < 72) {
        atomicAdd(&ps[col], s);
        atomicAdd(&ps[80 + col], q);
      }
      int growb = r0 + w * 16 + ((lane >> 4) << 2);
      if (col < 72) {
#pragma unroll
        for (int r = 0; r < 4; ++r)
          z[(size_t)(growb + r) * 72 + col] = (unsigned short)bfr(acc4[r]);
      }
    }
  }
  __syncthreads();
  if (tid < 160) atomicAdd(&stats[tid], ps[tid]);
}

// ---- FUSED: BN+act over Z -> ha (bf16, global) AND V = ha @ W2b + bias -> Vfc ----
__global__ __launch_bounds__(256) void k_hedge_post(
    const unsigned short* __restrict__ z, const float* __restrict__ stats,
    const float* __restrict__ gf, const float* __restrict__ bf_,
    const float* __restrict__ gc, const float* __restrict__ bc_,
    const float* __restrict__ f2wb, const float* __restrict__ c2wb,
    const float* __restrict__ f2b, const float* __restrict__ c2b,
    unsigned short* __restrict__ hab, unsigned* __restrict__ Vfc) {
  __shared__ float wf[35 * 64];
  __shared__ float wc[35 * 64];
  __shared__ float rs[16][36];
  __shared__ float sf[4][35];  // scaleF, shiftF, scaleC, shiftC
  int tid = threadIdx.x;
  for (int i = tid; i < 35 * 64; i += 256) {
    wf[i] = f2wb[i];
    wc[i] = c2wb[i];
  }
  if (tid < 35) {
    const float inv = 1.f / N_HEDGES;
    float mf = stats[tid] * inv;
    float vf = stats[80 + tid] * inv - mf * mf;
    float mc = stats[36 + tid] * inv;
    float vc = stats[116 + tid] * inv - mc * mc;
    float a = rsqrtf(vf + EPSB) * gf[tid];
    float b = rsqrtf(vc + EPSB) * gc[tid];
    sf[0][tid] = a;
    sf[1][tid] = bf_[tid] - mf * a;
    sf[2][tid] = b;
    sf[3][tid] = bc_[tid] - mc * b;
  }
  __syncthreads();
  int r0 = blockIdx.x * 16;
  for (int i = tid; i < 16 * 35; i += 256) {
    int r = i / 35, c = i - r * 35;
    const unsigned short* zr = &z[(size_t)(r0 + r) * 72];
    float nf = bf2f(zr[c]) * sf[0][c] + sf[1][c];
    float nc = bf2f(zr[36 + c]) * sf[2][c] + sf[3][c];
    float ha = sig_f(nf) * sp_f(nc);
    rs[r][c] = ha;
    hab[(size_t)(r0 + r) * 35 + c] = (unsigned short)bfr(ha);
  }
  __syncthreads();
  int h = tid & 63, rb = tid >> 6;
  float af0, af1, af2, af3, ac0, ac1, ac2, ac3;
  af0 = af1 = af2 = af3 = f2b[h];
  ac0 = ac1 = ac2 = ac3 = c2b[h];
  for (int k = 0; k < 35; ++k) {
    float wfv = wf[k * 64 + h], wcv = wc[k * 64 + h];
    float m0 = rs[rb][k], m1 = rs[rb + 4][k], m2 = rs[rb + 8][k], m3 = rs[rb + 12][k];
    af0 += m0 * wfv; ac0 += m0 * wcv;
    af1 += m1 * wfv; ac1 += m1 * wcv;
    af2 += m2 * wfv; ac2 += m2 * wcv;
    af3 += m3 * wfv; ac3 += m3 * wcv;
  }
  int row = r0 + rb;
  Vfc[row * 64 + h] = pk2(af0, ac0);
  Vfc[(row + 4) * 64 + h] = pk2(af1, ac1);
  Vfc[(row + 8) * 64 + h] = pk2(af2, ac2);
  Vfc[(row + 12) * 64 + h] = pk2(af3, ac3);
}

// ---- per-node projection: U = x @ W[0:64,:], bf16 in, packed bf16x2 out ----
__global__ __launch_bounds__(256) void k_uv_node(const unsigned short* __restrict__ xb,
                                                 const float* __restrict__ f2w,
                                                 const float* __restrict__ c2w,
                                                 unsigned* __restrict__ Ufc) {
  __shared__ float wf[64 * 64];
  __shared__ float wc[64 * 64];
  __shared__ float rs[16][65];
  int tid = threadIdx.x;
  for (int i = tid; i < 64 * 64; i += 256) {
    wf[i] = f2w[i];
    wc[i] = c2w[i];
  }
  int r0 = blockIdx.x * 16;
  for (int i = tid; i < 16 * 64; i += 256) {
    int r = i >> 6, k = i & 63;
    rs[r][k] = bf2f(xb[(size_t)(r0 + r) * 64 + k]);
  }
  __syncthreads();
  int h = tid & 63, rb = tid >> 6;
  float af0 = 0, af1 = 0, af2 = 0, af3 = 0, ac0 = 0, ac1 = 0, ac2 = 0, ac3 = 0;
  for (int k = 0; k < 64; ++k) {
    float wfv = wf[k * 64 + h], wcv = wc[k * 64 + h];
    float m0 = rs[rb][k], m1 = rs[rb + 4][k], m2 = rs[rb + 8][k], m3 = rs[rb + 12][k];
    af0 += m0 * wfv; ac0 += m0 * wcv;
    af1 += m1 * wfv; ac1 += m1 * wcv;
    af2 += m2 * wfv; ac2 += m2 * wcv;
    af3 += m3 * wfv; ac3 += m3 * wcv;
  }
  int row = r0 + rb;
  Ufc[row * 64 + h] = pk2(af0, ac0);
  Ufc[(row + 4) * 64 + h] = pk2(af1, ac1);
  Ufc[(row + 8) * 64 + h] = pk2(af2, ac2);
  Ufc[(row + 12) * 64 + h] = pk2(af3, ac3);
}

// ------ per-node aggregate: linear-entry 16-deep chunked walk + fused BN stats ------
__device__ __forceinline__ float act2(float uf, float uc, unsigned v) {
  float a = uf + blo(v);
  float b = uc + bhi(v);
  return sig_f(a) * sp_f(b);
}
// 4 waves x 16 nodes = 64 nodes/block; wave's perm range is contiguous (ordered CSR).
__global__ __launch_bounds__(256) void k_node_aggr(const int* __restrict__ permNh,
                                                   const int* __restrict__ offN,
                                                   const float* __restrict__ invdN,
                                                   const unsigned* __restrict__ Ufc,
                                                   const unsigned* __restrict__ Vfc,
                                                   unsigned short* __restrict__ ob,
                                                   float* __restrict__ stats) {
  __shared__ int bndL[4][18];
  __shared__ float ls[2][4][64];
  int tid = threadIdx.x;
  int w = tid >> 6, lane = tid & 63;  // lane = feature h
  int r0w = blockIdx.x * 64 + w * 16;
  if (lane < 17) bndL[w][lane] = offN[min(r0w + lane, N_NODES)];
  int eBeg = bndL[w][0], eEnd = bndL[w][16];

  int j = 0;
  int nb = bndL[w][1];
  float acc = 0.f, sacc = 0.f, qacc = 0.f;
  unsigned u0 = (r0w < N_NODES) ? Ufc[(size_t)r0w * 64 + lane] : 0u;
  float uf = blo(u0), uc = bhi(u0);

  for (int chunk = eBeg; chunk < eEnd; chunk += 16) {
    unsigned pv[16];
#pragma unroll
    for (int t = 0; t < 16; ++t) {
      int hg = permNh[min(chunk + t, eEnd - 1)];
      pv[t] = Vfc[(size_t)hg * 64 + lane];  // unconditional, 16 rows in flight
    }
#pragma unroll
    for (int t = 0; t < 16; ++t) {
      int e = chunk + t;
      if (e >= eEnd) break;
      while (e >= nb) {  // flush completed node j (wave-uniform)
        int row = r0w + j;
        float val = acc * invdN[row];
        ob[(size_t)row * 64 + lane] = (unsigned short)bfr(val);
        sacc += val;
        qacc += val * val;
        acc = 0.f;
        ++j;
        nb = bndL[w][j + 1];
        unsigned un = Ufc[(size_t)(r0w + j) * 64 + lane];
        uf = blo(un);
        uc = bhi(un);
      }
      acc += act2(uf, uc, pv[t]);
    }
  }
  for (; j < 16; ++j) {  // tail flush (incl. empty nodes)
    int row = r0w + j;
    if (row < N_NODES) {
      float val = acc * invdN[row];
      ob[(size_t)row * 64 + lane] = (unsigned short)bfr(val);
      sacc += val;
      qacc += val * val;
    }
    acc = 0.f;
  }

  ls[0][w][lane] = sacc;
  ls[1][w][lane] = qacc;
  __syncthreads();
  if (tid < 64) {
    atomicAdd(&stats[lane],
              ls[0][0][lane] + ls[0][1][lane] + ls[0][2][lane] + ls[0][3][lane]);
  } else if (tid < 128) {
    int hh = tid - 64;
    atomicAdd(&stats[64 + hh],
              ls[1][0][hh] + ls[1][1][hh] + ls[1][2][hh] + ls[1][3][hh]);
  }
}

// ---------- x = softplus(BN(o_mean) + x), bf16 o in, bf16 x in/out ----------
__global__ __launch_bounds__(256) void k_update(unsigned short* __restrict__ xb,
                                                const unsigned short* __restrict__ ob,
                                                const float* __restrict__ stats,
                                                const float* __restrict__ g,
                                                const float* __restrict__ b) {
  int t = blockIdx.x * 256 + threadIdx.x;
  int h = t & 63;
  float mean = stats[h] * (1.f / N_NODES);
  float var = stats[64 + h] * (1.f / N_NODES) - mean * mean;
  float is = rsqrtf(var + EPSB);
  float v = (bf2f(ob[t]) - mean) * is * g[h] + b[h];
  float r = sp_f(v + bf2f(xb[t]));
  xb[t] = (unsigned short)bfr(r);
}

// ------- graph pooling: chunked register accumulation (batch is sorted) -------
#define PR 512
__global__ __launch_bounds__(256) void k_pool(const unsigned short* __restrict__ xb,
                                              const int* __restrict__ batch,
                                              float* __restrict__ pooled,
                                              float* __restrict__ gcnt) {
  int h = threadIdx.x & 63, rs = threadIdx.x >> 6;
  int r0 = blockIdx.x * PR;
  int rend = min(r0 + PR, N_NODES);
  int gcur = -1;
  float acc = 0.f;
  int cnt = 0;
  for (int r = r0 + rs; r < rend; r += 4) {
    int g = batch[r];
    if (g != gcur) {
      if (gcur >= 0) {
        atomicAdd(&pooled[gcur * 64 + h], acc);
        if (h == 0) atomicAdd(&gcnt[gcur], (float)cnt);
      }
      gcur = g;
      acc = 0.f;
      cnt = 0;
    }
    acc += bf2f(xb[(size_t)r * 64 + h]);
    cnt++;
  }
  if (gcur >= 0) {
    atomicAdd(&pooled[gcur * 64 + h], acc);
    if (h == 0) atomicAdd(&gcnt[gcur], (float)cnt);
  }
}

// -------------------- final dense layers --------------------
__global__ __launch_bounds__(128) void k_final(const float* __restrict__ pooled,
                                               const float* __restrict__ gcnt,
                                               const float* __restrict__ l2w,
                                               const float* __restrict__ l2b,
                                               const float* __restrict__ ow,
                                               const float* __restrict__ ob,
                                               float* __restrict__ out) {
  int g = blockIdx.x;
  int t = threadIdx.x;
  __shared__ float row[64];
  __shared__ float hh[128];
  if (t < 64) row[t] = pooled[g * 64 + t] / fmaxf(gcnt[g], 1.f);
  __syncthreads();
  float acc = l2b[t];
  for (int k = 0; k < 64; ++k) acc += row[k] * l2w[k * 128 + t];
  hh[t] = sp_f(acc) * ow[t];
  __syncthreads();
  for (int s = 64; s > 0; s >>= 1) {
    if (t < s) hh[t] += hh[t + s];
    __syncthreads();
  }
  if (t == 0) out[g] = hh[0] + ob[0];
}

extern "C" void kernel_launch(void* const* d_in, const int* in_sizes, int n_in,
                              void* d_out, int out_size, void* d_ws, size_t ws_size,
                              hipStream_t stream) {
  const float* x_in = (const float*)d_in[0];
  const int* node_idx = (const int*)d_in[1];
  const int* hedge_idx = (const int*)d_in[2];
  const float* hedge_attr = (const float*)d_in[3];
  const int* batch = (const int*)d_in[4];
  const float* embed_w = (const float*)d_in[5];
  const float* embed_b = (const float*)d_in[6];
  const float* f1_w = (const float*)d_in[7];
  const float* c1_w = (const float*)d_in[9];
  const float* f2_w = (const float*)d_in[11];
  const float* f2_b = (const float*)d_in[12];
  const float* c2_w = (const float*)d_in[13];
  const float* c2_b = (const float*)d_in[14];
  const float* bnf_g = (const float*)d_in[15];
  const float* bnf_b = (const float*)d_in[16];
  const float* bnc_g = (const float*)d_in[17];
  const float* bnc_b = (const float*)d_in[18];
  const float* bno_g = (const float*)d_in[19];
  const float* bno_b = (const float*)d_in[20];
  const float* l2_w = (const float*)d_in[21];
  const float* l2_b = (const float*)d_in[22];
  const float* out_w = (const float*)d_in[23];
  const float* out_b = (const float*)d_in[24];

  // workspace layout (bytes, 256-aligned)
  char* base = (char*)d_ws;
  size_t off = 0;
  auto alloc = [&](size_t bytes) {
    size_t o = off;
    off = (off + bytes + 255) & ~(size_t)255;
    return o;
  };
  unsigned short* xbf = (unsigned short*)(base + alloc((size_t)N_NODES * 64 * 2));
  unsigned short* hab = (unsigned short*)(base + alloc((size_t)N_HEDGES * 35 * 2));
  unsigned* Vfc = (unsigned*)(base + alloc((size_t)N_HEDGES * 64 * 4));
  unsigned short* zbuf = (unsigned short*)(base + alloc((size_t)N_HEDGES * 72 * 2));
  unsigned short* obuf = (unsigned short*)(base + alloc((size_t)N_NODES * 64 * 2));
  unsigned* Ufc = (unsigned*)(base + alloc((size_t)N_NODES * 64 * 4));
  uint4* wpk = (uint4*)(base + alloc((size_t)60 * 64 * 16));
  float* hstatsA = (float*)(base + alloc(3 * 160 * 4));
  float* ostatsA = (float*)(base + alloc(3 * 128 * 4));
  float* pooled = (float*)(base + alloc((size_t)N_GRAPHS * 64 * 4));
  float* gcnt = (float*)(base + alloc((size_t)N_GRAPHS * 4));
  int* degH = (int*)(base + alloc((size_t)N_HEDGES * 4));  // degH|degN adjacent memset
  int* degN = (int*)(base + alloc((size_t)N_NODES * 4));
  int* offH = (int*)(base + alloc((size_t)(N_HEDGES + 1) * 4));  // +1 sentinel
  int* offN = (int*)(base + alloc((size_t)(N_NODES + 1) * 4));   // +1 sentinel
  float* invdH = (float*)(base + alloc((size_t)N_HEDGES * 4));
  float* invdN = (float*)(base + alloc((size_t)N_NODES * 4));
  int* bsum = (int*)(base + alloc((size_t)(CHB + CNB) * 4));
  int* rankH = (int*)(base + alloc((size_t)N_INC * 4));
  int* rankN = (int*)(base + alloc((size_t)N_INC * 4));
  int* permHn = (int*)(base + alloc((size_t)N_INC * 4));
  int* permNh = (int*)(base + alloc((size_t)N_INC * 4));
  (void)ws_size;
  (void)in_sizes;
  (void)n_in;
  (void)out_size;

  // ---- ordered CSR build ----
  hipMemsetAsync(degH, 0,
                 (size_t)((char*)degN - (char*)degH) + (size_t)N_NODES * 4, stream);
  k_hist<<<(N_INC + 255) / 256, 256, 0, stream>>>(node_idx, hedge_idx, degN, degH,
                                                  rankN, rankH);
  k_bsum<<<CHB + CNB, 256, 0, stream>>>(degH, degN, bsum);
  k_bscan<<<2, 64, 0, stream>>>(bsum);
  k_alloc2<<<CHB + CNB, 256, 0, stream>>>(degH, degN, bsum, offH, offN, invdH, invdN);
  k_fill<<<(N_INC + 255) / 256, 256, 0, stream>>>(node_idx, hedge_idx, rankH, rankN,
                                                  offH, offN, permHn, permNh,
                                                  &offH[N_HEDGES], &offN[N_NODES]);
  k_wpack<<<60, 64, 0, stream>>>(f1_w, c1_w, wpk);
  k_cvt_ha<<<(N_HEDGES * 35 + 255) / 256, 256, 0, stream>>>(hedge_attr, hab,
                                                            N_HEDGES * 35);
  k_embed<<<N_NODES / 16, 256, 0, stream>>>(x_in, embed_w, embed_b, xbf);

  // zero all per-layer stats in one go
  hipMemsetAsync(hstatsA, 0, (size_t)((char*)ostatsA - (char*)hstatsA) + 3 * 128 * 4,
                 stream);

  for (int i = 0; i < 3; ++i) {
    float* hstats = hstatsA + i * 160;
    float* ostats = ostatsA + i * 128;

    // fused pipelined gather + MFMA GEMM + stats
    k_hedge_gemm<<<N_HEDGES / GR, 256, 0, stream>>>(
        xbf, permHn, offH, invdH, hab, wpk + (size_t)i * 20 * 64, zbuf, hstats);
    // fused BN+act -> ha + V-projection
    k_hedge_post<<<N_HEDGES / 16, 256, 0, stream>>>(
        zbuf, hstats, bnf_g + i * HE, bnf_b + i * HE, bnc_g + i * HE, bnc_b + i * HE,
        f2_w + i * CAT * 64 + 64 * 64, c2_w + i * CAT * 64 + 64 * 64,
        f2_b + i * 64, c2_b + i * 64, hab, Vfc);

    // node projection
    k_uv_node<<<N_NODES / 16, 256, 0, stream>>>(xbf, f2_w + i * CAT * 64,
                                                c2_w + i * CAT * 64, Ufc);

    // per-node combine (linear-entry chunked walk) + fused BN stats
    k_node_aggr<<<(N_NODES + 63) / 64, 256, 0, stream>>>(permNh, offN, invdN, Ufc,
                                                         Vfc, obuf, ostats);

    // node BN + residual softplus
    k_update<<<N_NODES * 64 / 256, 256, 0, stream>>>(xbf, obuf, ostats,
                                                     bno_g + i * 64, bno_b + i * 64);
  }

  // pooling + head
  hipMemsetAsync(pooled, 0, (size_t)((char*)gcnt - (char*)pooled) + N_GRAPHS * 4,
                 stream);
  k_pool<<<(N_NODES + PR - 1) / PR, 256, 0, stream>>>(xbf, batch, pooled, gcnt);
  k_final<<<N_GRAPHS, 128, 0, stream>>>(pooled, gcnt, l2_w, l2_b, out_w, out_b,
                                        (float*)d_out);
}

// Round 14
// 1202.971 us; speedup vs baseline: 1.0790x; 1.0255x over previous
//
#include <hip/hip_runtime.h>
#include <math.h>

#define N_NODES 100000
#define N_HEDGES 200000
#define N_INC 1000000
#define N_GRAPHS 256
#define HD 64
#define HE 35
#define CAT 99
#define EPSB 1e-5f

typedef __attribute__((ext_vector_type(8))) short short8;
typedef __attribute__((ext_vector_type(4))) float f32x4;

__device__ __forceinline__ float sp_f(float x) {
  return fmaxf(x, 0.f) + __logf(1.f + __expf(-fabsf(x)));
}
__device__ __forceinline__ float sig_f(float x) {
  return __builtin_amdgcn_rcpf(1.f + __expf(-x));
}
__device__ __forceinline__ unsigned bfr(float x) {
  unsigned u = __float_as_uint(x);
  return (u + 0x7fffu + ((u >> 16) & 1u)) >> 16;
}
__device__ __forceinline__ unsigned pk2(float lo, float hi) {
  return bfr(lo) | (bfr(hi) << 16);
}
__device__ __forceinline__ float blo(unsigned v) { return __uint_as_float(v << 16); }
__device__ __forceinline__ float bhi(unsigned v) {
  return __uint_as_float(v & 0xffff0000u);
}
__device__ __forceinline__ float bf2f(unsigned short s) {
  return __uint_as_float(((unsigned)s) << 16);
}

// ---- histogram + within-segment ranks ----
__global__ __launch_bounds__(256) void k_hist(const int* __restrict__ nidx,
                                              const int* __restrict__ hidx,
                                              int* __restrict__ degN,
                                              int* __restrict__ degH,
                                              int* __restrict__ rankN,
                                              int* __restrict__ rankH) {
  int e = blockIdx.x * 256 + threadIdx.x;
  if (e >= N_INC) return;
  rankH[e] = atomicAdd(&degH[hidx[e]], 1);
  rankN[e] = atomicAdd(&degN[nidx[e]], 1);
}

#define CHB ((N_HEDGES + 255) / 256)
#define CNB ((N_NODES + 255) / 256)

// ---- per-256-chunk degree sums (both segmentations) ----
__global__ __launch_bounds__(256) void k_bsum(const int* __restrict__ degH,
                                              const int* __restrict__ degN,
                                              int* __restrict__ bsum) {
  __shared__ int s[256];
  int b = blockIdx.x, t = threadIdx.x;
  const int* deg;
  int n, i;
  if (b < CHB) {
    deg = degH; n = N_HEDGES; i = b * 256 + t;
  } else {
    deg = degN; n = N_NODES; i = (b - CHB) * 256 + t;
  }
  s[t] = (i < n) ? deg[i] : 0;
  __syncthreads();
  for (int st = 128; st > 0; st >>= 1) {
    if (t < st) s[t] += s[t + st];
    __syncthreads();
  }
  if (t == 0) bsum[b] = s[0];
}

// ---- exclusive scan of chunk sums, per segment ----
__global__ __launch_bounds__(64) void k_bscan(int* __restrict__ bsum) {
  int seg0 = (blockIdx.x == 0) ? 0 : CHB;
  int segn = (blockIdx.x == 0) ? CHB : CNB;
  int lane = threadIdx.x;
  int carry = 0;
  for (int base = 0; base < segn; base += 64) {
    int i = base + lane;
    int orig = (i < segn) ? bsum[seg0 + i] : 0;
    int v = orig;
    for (int st = 1; st < 64; st <<= 1) {
      int u = __shfl_up(v, st);
      if (lane >= st) v += u;
    }
    int total = __shfl(v, 63);
    if (i < segn) bsum[seg0 + i] = carry + (v - orig);
    carry += total;
  }
}

// ---- ordered CSR offsets (+ reciprocal degrees both sides) ----
__global__ __launch_bounds__(256) void k_alloc2(const int* __restrict__ degH,
                                                const int* __restrict__ degN,
                                                const int* __restrict__ bsum,
                                                int* __restrict__ offH,
                                                int* __restrict__ offN,
                                                float* __restrict__ invdH,
                                                float* __restrict__ invdN) {
  __shared__ int s[256];
  int b = blockIdx.x, t = threadIdx.x;
  const int* deg;
  int* off;
  int n, i;
  bool isH = (b < CHB);
  if (isH) {
    deg = degH; off = offH; n = N_HEDGES; i = b * 256 + t;
  } else {
    deg = degN; off = offN; n = N_NODES; i = (b - CHB) * 256 + t;
  }
  int d = (i < n) ? deg[i] : 0;
  s[t] = d;
  __syncthreads();
  for (int st = 1; st < 256; st <<= 1) {
    int u = 0;
    if (t >= st) u = s[t - st];
    __syncthreads();
    if (t >= st) s[t] += u;
    __syncthreads();
  }
  if (i < n) {
    off[i] = s[t] - d + bsum[b];
    if (isH)
      invdH[i] = 1.f / (float)max(d, 1);
    else
      invdN[i] = 1.f / (float)max(d, 1);
  }
}

// ---- atomic-free CSR fill (+ both sentinels) ----
__global__ __launch_bounds__(256) void k_fill(const int* __restrict__ nidx,
                                              const int* __restrict__ hidx,
                                              const int* __restrict__ rankH,
                                              const int* __restrict__ rankN,
                                              const int* __restrict__ offH,
                                              const int* __restrict__ offN,
                                              int* __restrict__ permHn,
                                              int* __restrict__ permNh,
                                              int* __restrict__ offH_sent,
                                              int* __restrict__ offN_sent) {
  int e = blockIdx.x * 256 + threadIdx.x;
  if (e >= N_INC) return;
  if (e == 0) {
    *offH_sent = N_INC;  // offH[N_HEDGES]
    *offN_sent = N_INC;  // offN[N_NODES]
  }
  int nd = nidx[e], hg = hidx[e];
  permHn[offH[hg] + rankH[e]] = nd;
  permNh[offN[nd] + rankN[e]] = hg;
}

// ---- weight prepack: B[k=0..127][col=0..79] = [Wf | Wc | pad] as MFMA B-frags ----
__global__ __launch_bounds__(64) void k_wpack(const float* __restrict__ f1w,
                                              const float* __restrict__ c1w,
                                              uint4* __restrict__ wpk) {
  int b = blockIdx.x;  // 60 = 3 layers * 5 ct * 4 ks
  int layer = b / 20, rem = b % 20, ct = rem / 4, ks = rem % 4;
  int lane = threadIdx.x;
  int col = ct * 16 + (lane & 15);
  int k0 = ks * 32 + (lane >> 4) * 8;
  const float* wf = f1w + layer * CAT * HE;
  const float* wc = c1w + layer * CAT * HE;
  unsigned v[4];
#pragma unroll
  for (int p = 0; p < 4; ++p) {
    float lo = 0.f, hi = 0.f;
    int ka = k0 + p * 2, kb = ka + 1;
    if (ka < 99) {
      if (col < 35) lo = wf[ka * 35 + col];
      else if (col >= 36 && col < 71) lo = wc[ka * 35 + (col - 36)];
    }
    if (kb < 99) {
      if (col < 35) hi = wf[kb * 35 + col];
      else if (col >= 36 && col < 71) hi = wc[kb * 35 + (col - 36)];
    }
    v[p] = pk2(lo, hi);
  }
  uint4 o;
  o.x = v[0]; o.y = v[1]; o.z = v[2]; o.w = v[3];
  wpk[b * 64 + lane] = o;
}

// -------------------- embed: x[N,92] @ w[92,64] + b -> bf16 --------------------
__global__ __launch_bounds__(256) void k_embed(const float* __restrict__ x,
                                               const float* __restrict__ w,
                                               const float* __restrict__ b,
                                               unsigned short* __restrict__ outb) {
  __shared__ float ws[92 * 64];
  __shared__ float rs[16][93];
  int tid = threadIdx.x;
  for (int i = tid; i < 92 * 64; i += 256) ws[i] = w[i];
  int r0 = blockIdx.x * 16;
  for (int i = tid; i < 16 * 92; i += 256) {
    int r = i / 92, k = i - r * 92;
    rs[r][k] = x[(r0 + r) * 92 + k];
  }
  __syncthreads();
  int h = tid & 63;
  float bias = b[h];
  for (int rr = tid >> 6; rr < 16; rr += 4) {
    float acc = bias;
    for (int k = 0; k < 92; ++k) acc += rs[rr][k] * ws[k * 64 + h];
    outb[(r0 + rr) * 64 + h] = (unsigned short)bfr(acc);
  }
}

// ------ FUSED hedge gather (linear-entry, 16-deep) + MFMA GEMM ------
// L0: stage ha from f32 hedge_attr directly (no cvt kernel).
#define GR 64
template <bool L0>
__global__ __launch_bounds__(256) void k_hedge_gemm(
    const unsigned short* __restrict__ xb, const int* __restrict__ permHn,
    const int* __restrict__ offH, const float* __restrict__ invdH,
    const unsigned short* __restrict__ hab, const float* __restrict__ haf,
    const uint4* __restrict__ wpk, unsigned short* __restrict__ z,
    float* __restrict__ stats) {
  __shared__ unsigned short msg[GR * 128];
  __shared__ float ps[160];
  __shared__ int bndL[4][18];
  int tid = threadIdx.x;
  int w = tid >> 6, lane = tid & 63;
  int r0 = blockIdx.x * GR;
  if (tid < 160) ps[tid] = 0.f;

  // B-fragments (L2-resident)
  short8 bfg[5][4];
#pragma unroll
  for (int ct = 0; ct < 5; ++ct)
#pragma unroll
    for (int ks = 0; ks < 4; ++ks)
      bfg[ct][ks] = __builtin_bit_cast(short8, wpk[(ct * 4 + ks) * 64 + lane]);

  char* mb = (char*)msg;
  // cooperative ha staging into msg cols 64..127 (zero-padded past 98)
  for (int i = tid; i < GR * 64; i += 256) {
    int r = i >> 6, c = 64 + (i & 63);
    unsigned short hv = 0;
    if (c < 99) {
      if (L0)
        hv = (unsigned short)bfr(haf[(size_t)(r0 + r) * 35 + (c - 64)]);
      else
        hv = hab[(size_t)(r0 + r) * 35 + (c - 64)];
    }
    *(unsigned short*)(mb + ((r * 256 + c * 2) ^ ((r & 7) << 4))) = hv;
  }

  // per-wave row bounds (17 values; offH has sentinel at N_HEDGES)
  int r0w = r0 + w * 16;
  if (lane < 17) bndL[w][lane] = offH[r0w + lane];
  int eBeg = bndL[w][0], eEnd = bndL[w][16];

  int j = 0;
  int nb = bndL[w][1];
  float acc = 0.f;
  for (int chunk = eBeg; chunk < eEnd; chunk += 16) {
    float v[16];
#pragma unroll
    for (int t = 0; t < 16; ++t) {
      int idx = permHn[min(chunk + t, eEnd - 1)];
      v[t] = bf2f(xb[(size_t)idx * 64 + lane]);  // unconditional, 16-deep cluster
    }
#pragma unroll
    for (int t = 0; t < 16; ++t) {
      int e = chunk + t;
      if (e >= eEnd) break;
      while (e >= nb) {  // flush completed row j (wave-uniform)
        int rl = w * 16 + j;
        unsigned short mv = (unsigned short)bfr(acc * invdH[r0w + j]);
        *(unsigned short*)(mb + ((rl * 256 + lane * 2) ^ ((rl & 7) << 4))) = mv;
        acc = 0.f;
        ++j;
        nb = bndL[w][j + 1];
      }
      acc += v[t];
    }
  }
  for (; j < 16; ++j) {  // tail flush (incl. empty rows)
    int rl = w * 16 + j;
    unsigned short mv = (unsigned short)bfr(acc * invdH[r0w + j]);
    *(unsigned short*)(mb + ((rl * 256 + lane * 2) ^ ((rl & 7) << 4))) = mv;
    acc = 0.f;
  }
  __syncthreads();

  // MFMA + stats + bf16 Z write (one 16-row tile per wave)
  {
    int rloc = w * 16 + (lane & 15);
    short8 a[4];
#pragma unroll
    for (int ks = 0; ks < 4; ++ks) {
      int byte = rloc * 256 + (ks * 32 + (lane >> 4) * 8) * 2;
      a[ks] = *(const short8*)(mb + (byte ^ ((rloc & 7) << 4)));
    }
#pragma unroll
    for (int ct = 0; ct < 5; ++ct) {
      f32x4 acc4 = {0.f, 0.f, 0.f, 0.f};
#pragma unroll
      for (int ks = 0; ks < 4; ++ks)
        acc4 = __builtin_amdgcn_mfma_f32_16x16x32_bf16(a[ks], bfg[ct][ks], acc4, 0, 0, 0);
      float s = (acc4[0] + acc4[1]) + (acc4[2] + acc4[3]);
      float q = (acc4[0] * acc4[0] + acc4[1] * acc4[1]) +
                (acc4[2] * acc4[2] + acc4[3] * acc4[3]);
      s += __shfl_xor(s, 16);
      s += __shfl_xor(s, 32);
      q += __shfl_xor(q, 16);
      q += __shfl_xor(q, 32);
      int col = ct * 16 + (lane & 15);
      if ((lane >> 4) == 0 && col < 72) {
        atomicAdd(&ps[col], s);
        atomicAdd(&ps[80 + col], q);
      }
      int growb = r0 + w * 16 + ((lane >> 4) << 2);
      if (col < 72) {
#pragma unroll
        for (int r = 0; r < 4; ++r)
          z[(size_t)(growb + r) * 72 + col] = (unsigned short)bfr(acc4[r]);
      }
    }
  }
  __syncthreads();
  if (tid < 160) atomicAdd(&stats[tid], ps[tid]);
}

// ---- FUSED: BN+act over Z -> ha (bf16, optional) AND V = ha @ W2b + bias -> Vfc ----
__global__ __launch_bounds__(256) void k_hedge_post(
    const unsigned short* __restrict__ z, const float* __restrict__ stats,
    const float* __restrict__ gf, const float* __restrict__ bf_,
    const float* __restrict__ gc, const float* __restrict__ bc_,
    const float* __restrict__ f2wb, const float* __restrict__ c2wb,
    const float* __restrict__ f2b, const float* __restrict__ c2b,
    unsigned short* __restrict__ hab, unsigned* __restrict__ Vfc, int writeHa) {
  __shared__ float wf[35 * 64];
  __shared__ float wc[35 * 64];
  __shared__ float rs[16][36];
  __shared__ float sf[4][35];  // scaleF, shiftF, scaleC, shiftC
  int tid = threadIdx.x;
  for (int i = tid; i < 35 * 64; i += 256) {
    wf[i] = f2wb[i];
    wc[i] = c2wb[i];
  }
  if (tid < 35) {
    const float inv = 1.f / N_HEDGES;
    float mf = stats[tid] * inv;
    float vf = stats[80 + tid] * inv - mf * mf;
    float mc = stats[36 + tid] * inv;
    float vc = stats[116 + tid] * inv - mc * mc;
    float a = rsqrtf(vf + EPSB) * gf[tid];
    float b = rsqrtf(vc + EPSB) * gc[tid];
    sf[0][tid] = a;
    sf[1][tid] = bf_[tid] - mf * a;
    sf[2][tid] = b;
    sf[3][tid] = bc_[tid] - mc * b;
  }
  __syncthreads();
  int r0 = blockIdx.x * 16;
  for (int i = tid; i < 16 * 35; i += 256) {
    int r = i / 35, c = i - r * 35;
    const unsigned short* zr = &z[(size_t)(r0 + r) * 72];
    float nf = bf2f(zr[c]) * sf[0][c] + sf[1][c];
    float nc = bf2f(zr[36 + c]) * sf[2][c] + sf[3][c];
    float ha = sig_f(nf) * sp_f(nc);
    rs[r][c] = ha;
    if (writeHa) hab[(size_t)(r0 + r) * 35 + c] = (unsigned short)bfr(ha);
  }
  __syncthreads();
  int h = tid & 63, rb = tid >> 6;
  float af0, af1, af2, af3, ac0, ac1, ac2, ac3;
  af0 = af1 = af2 = af3 = f2b[h];
  ac0 = ac1 = ac2 = ac3 = c2b[h];
  for (int k = 0; k < 35; ++k) {
    float wfv = wf[k * 64 + h], wcv = wc[k * 64 + h];
    float m0 = rs[rb][k], m1 = rs[rb + 4][k], m2 = rs[rb + 8][k], m3 = rs[rb + 12][k];
    af0 += m0 * wfv; ac0 += m0 * wcv;
    af1 += m1 * wfv; ac1 += m1 * wcv;
    af2 += m2 * wfv; ac2 += m2 * wcv;
    af3 += m3 * wfv; ac3 += m3 * wcv;
  }
  int row = r0 + rb;
  Vfc[row * 64 + h] = pk2(af0, ac0);
  Vfc[(row + 4) * 64 + h] = pk2(af1, ac1);
  Vfc[(row + 8) * 64 + h] = pk2(af2, ac2);
  Vfc[(row + 12) * 64 + h] = pk2(af3, ac3);
}

// ---- per-node projection (layer 0 only): U = x @ W[0:64,:], bf16 in ----
__global__ __launch_bounds__(256) void k_uv_node(const unsigned short* __restrict__ xb,
                                                 const float* __restrict__ f2w,
                                                 const float* __restrict__ c2w,
                                                 unsigned* __restrict__ Ufc) {
  __shared__ float wf[64 * 64];
  __shared__ float wc[64 * 64];
  __shared__ float rs[16][65];
  int tid = threadIdx.x;
  for (int i = tid; i < 64 * 64; i += 256) {
    wf[i] = f2w[i];
    wc[i] = c2w[i];
  }
  int r0 = blockIdx.x * 16;
  for (int i = tid; i < 16 * 64; i += 256) {
    int r = i >> 6, k = i & 63;
    rs[r][k] = bf2f(xb[(size_t)(r0 + r) * 64 + k]);
  }
  __syncthreads();
  int h = tid & 63, rb = tid >> 6;
  float af0 = 0, af1 = 0, af2 = 0, af3 = 0, ac0 = 0, ac1 = 0, ac2 = 0, ac3 = 0;
  for (int k = 0; k < 64; ++k) {
    float wfv = wf[k * 64 + h], wcv = wc[k * 64 + h];
    float m0 = rs[rb][k], m1 = rs[rb + 4][k], m2 = rs[rb + 8][k], m3 = rs[rb + 12][k];
    af0 += m0 * wfv; ac0 += m0 * wcv;
    af1 += m1 * wfv; ac1 += m1 * wcv;
    af2 += m2 * wfv; ac2 += m2 * wcv;
    af3 += m3 * wfv; ac3 += m3 * wcv;
  }
  int row = r0 + rb;
  Ufc[row * 64 + h] = pk2(af0, ac0);
  Ufc[(row + 4) * 64 + h] = pk2(af1, ac1);
  Ufc[(row + 8) * 64 + h] = pk2(af2, ac2);
  Ufc[(row + 12) * 64 + h] = pk2(af3, ac3);
}

// ------ per-node aggregate: linear-entry 16-deep chunked walk + fused BN stats ------
__device__ __forceinline__ float act2(float uf, float uc, unsigned v) {
  float a = uf + blo(v);
  float b = uc + bhi(v);
  return sig_f(a) * sp_f(b);
}
__global__ __launch_bounds__(256) void k_node_aggr(const int* __restrict__ permNh,
                                                   const int* __restrict__ offN,
                                                   const float* __restrict__ invdN,
                                                   const unsigned* __restrict__ Ufc,
                                                   const unsigned* __restrict__ Vfc,
                                                   unsigned short* __restrict__ ob,
                                                   float* __restrict__ stats) {
  __shared__ int bndL[4][18];
  __shared__ float ls[2][4][64];
  int tid = threadIdx.x;
  int w = tid >> 6, lane = tid & 63;  // lane = feature h
  int r0w = blockIdx.x * 64 + w * 16;
  if (lane < 17) bndL[w][lane] = offN[min(r0w + lane, N_NODES)];
  int eBeg = bndL[w][0], eEnd = bndL[w][16];

  int j = 0;
  int nb = bndL[w][1];
  float acc = 0.f, sacc = 0.f, qacc = 0.f;
  unsigned u0 = (r0w < N_NODES) ? Ufc[(size_t)r0w * 64 + lane] : 0u;
  float uf = blo(u0), uc = bhi(u0);

  for (int chunk = eBeg; chunk < eEnd; chunk += 16) {
    unsigned pv[16];
#pragma unroll
    for (int t = 0; t < 16; ++t) {
      int hg = permNh[min(chunk + t, eEnd - 1)];
      pv[t] = Vfc[(size_t)hg * 64 + lane];  // unconditional, 16 rows in flight
    }
#pragma unroll
    for (int t = 0; t < 16; ++t) {
      int e = chunk + t;
      if (e >= eEnd) break;
      while (e >= nb) {  // flush completed node j (wave-uniform)
        int row = r0w + j;
        float val = acc * invdN[row];
        ob[(size_t)row * 64 + lane] = (unsigned short)bfr(val);
        sacc += val;
        qacc += val * val;
        acc = 0.f;
        ++j;
        nb = bndL[w][j + 1];
        unsigned un = Ufc[(size_t)(r0w + j) * 64 + lane];
        uf = blo(un);
        uc = bhi(un);
      }
      acc += act2(uf, uc, pv[t]);
    }
  }
  for (; j < 16; ++j) {  // tail flush (incl. empty nodes)
    int row = r0w + j;
    if (row < N_NODES) {
      float val = acc * invdN[row];
      ob[(size_t)row * 64 + lane] = (unsigned short)bfr(val);
      sacc += val;
      qacc += val * val;
    }
    acc = 0.f;
  }

  ls[0][w][lane] = sacc;
  ls[1][w][lane] = qacc;
  __syncthreads();
  if (tid < 64) {
    atomicAdd(&stats[lane],
              ls[0][0][lane] + ls[0][1][lane] + ls[0][2][lane] + ls[0][3][lane]);
  } else if (tid < 128) {
    int hh = tid - 64;
    atomicAdd(&stats[64 + hh],
              ls[1][0][hh] + ls[1][1][hh] + ls[1][2][hh] + ls[1][3][hh]);
  }
}

// -- FUSED: x = softplus(BN(o)+x) AND U(next layer) = x @ W -> Ufc (16 rows/block) --
__global__ __launch_bounds__(256) void k_update_uv(
    unsigned short* __restrict__ xb, const unsigned short* __restrict__ ob,
    const float* __restrict__ stats, const float* __restrict__ g,
    const float* __restrict__ b, const float* __restrict__ f2w,
    const float* __restrict__ c2w, unsigned* __restrict__ Ufc) {
  __shared__ float wf[64 * 64];
  __shared__ float wc[64 * 64];
  __shared__ float rs[16][65];
  int tid = threadIdx.x;
  for (int i = tid; i < 64 * 64; i += 256) {
    wf[i] = f2w[i];
    wc[i] = c2w[i];
  }
  int r0 = blockIdx.x * 16;
  int h = tid & 63, rb = tid >> 6;
  float mean = stats[h] * (1.f / N_NODES);
  float var = stats[64 + h] * (1.f / N_NODES) - mean * mean;
  float is = rsqrtf(var + EPSB);
  float gh = g[h], bh = b[h];
#pragma unroll
  for (int j = 0; j < 16; j += 4) {
    size_t t = (size_t)(r0 + rb + j) * 64 + h;
    float v = (bf2f(ob[t]) - mean) * is * gh + bh;
    float r = sp_f(v + bf2f(xb[t]));
    xb[t] = (unsigned short)bfr(r);
    rs[rb + j][h] = r;
  }
  __syncthreads();
  float af0 = 0, af1 = 0, af2 = 0, af3 = 0, ac0 = 0, ac1 = 0, ac2 = 0, ac3 = 0;
  for (int k = 0; k < 64; ++k) {
    float wfv = wf[k * 64 + h], wcv = wc[k * 64 + h];
    float m0 = rs[rb][k], m1 = rs[rb + 4][k], m2 = rs[rb + 8][k], m3 = rs[rb + 12][k];
    af0 += m0 * wfv; ac0 += m0 * wcv;
    af1 += m1 * wfv; ac1 += m1 * wcv;
    af2 += m2 * wfv; ac2 += m2 * wcv;
    af3 += m3 * wfv; ac3 += m3 * wcv;
  }
  int row = r0 + rb;
  Ufc[row * 64 + h] = pk2(af0, ac0);
  Ufc[(row + 4) * 64 + h] = pk2(af1, ac1);
  Ufc[(row + 8) * 64 + h] = pk2(af2, ac2);
  Ufc[(row + 12) * 64 + h] = pk2(af3, ac3);
}

// ---------- plain update (last layer): x = softplus(BN(o_mean) + x) ----------
__global__ __launch_bounds__(256) void k_update(unsigned short* __restrict__ xb,
                                                const unsigned short* __restrict__ ob,
                                                const float* __restrict__ stats,
                                                const float* __restrict__ g,
                                                const float* __restrict__ b) {
  int t = blockIdx.x * 256 + threadIdx.x;
  int h = t & 63;
  float mean = stats[h] * (1.f / N_NODES);
  float var = stats[64 + h] * (1.f / N_NODES) - mean * mean;
  float is = rsqrtf(var + EPSB);
  float v = (bf2f(ob[t]) - mean) * is * g[h] + b[h];
  float r = sp_f(v + bf2f(xb[t]));
  xb[t] = (unsigned short)bfr(r);
}

// ------- graph pooling: chunked register accumulation (batch is sorted) -------
#define PR 512
__global__ __launch_bounds__(256) void k_pool(const unsigned short* __restrict__ xb,
                                              const int* __restrict__ batch,
                                              float* __restrict__ pooled,
                                              float* __restrict__ gcnt) {
  int h = threadIdx.x & 63, rs = threadIdx.x >> 6;
  int r0 = blockIdx.x * PR;
  int rend = min(r0 + PR, N_NODES);
  int gcur = -1;
  float acc = 0.f;
  int cnt = 0;
  for (int r = r0 + rs; r < rend; r += 4) {
    int g = batch[r];
    if (g != gcur) {
      if (gcur >= 0) {
        atomicAdd(&pooled[gcur * 64 + h], acc);
        if (h == 0) atomicAdd(&gcnt[gcur], (float)cnt);
      }
      gcur = g;
      acc = 0.f;
      cnt = 0;
    }
    acc += bf2f(xb[(size_t)r * 64 + h]);
    cnt++;
  }
  if (gcur >= 0) {
    atomicAdd(&pooled[gcur * 64 + h], acc);
    if (h == 0) atomicAdd(&gcnt[gcur], (float)cnt);
  }
}

// -------------------- final dense layers --------------------
__global__ __launch_bounds__(128) void k_final(const float* __restrict__ pooled,
                                               const float* __restrict__ gcnt,
                                               const float* __restrict__ l2w,
                                               const float* __restrict__ l2b,
                                               const float* __restrict__ ow,
                                               const float* __restrict__ ob,
                                               float* __restrict__ out) {
  int g = blockIdx.x;
  int t = threadIdx.x;
  __shared__ float row[64];
  __shared__ float hh[128];
  if (t < 64) row[t] = pooled[g * 64 + t] / fmaxf(gcnt[g], 1.f);
  __syncthreads();
  float acc = l2b[t];
  for (int k = 0; k < 64; ++k) acc += row[k] * l2w[k * 128 + t];
  hh[t] = sp_f(acc) * ow[t];
  __syncthreads();
  for (int s = 64; s > 0; s >>= 1) {
    if (t < s) hh[t] += hh[t + s];
    __syncthreads();
  }
  if (t == 0) out[g] = hh[0] + ob[0];
}

extern "C" void kernel_launch(void* const* d_in, const int* in_sizes, int n_in,
                              void* d_out, int out_size, void* d_ws, size_t ws_size,
                              hipStream_t stream) {
  const float* x_in = (const float*)d_in[0];
  const int* node_idx = (const int*)d_in[1];
  const int* hedge_idx = (const int*)d_in[2];
  const float* hedge_attr = (const float*)d_in[3];
  const int* batch = (const int*)d_in[4];
  const float* embed_w = (const float*)d_in[5];
  const float* embed_b = (const float*)d_in[6];
  const float* f1_w = (const float*)d_in[7];
  const float* c1_w = (const float*)d_in[9];
  const float* f2_w = (const float*)d_in[11];
  const float* f2_b = (const float*)d_in[12];
  const float* c2_w = (const float*)d_in[13];
  const float* c2_b = (const float*)d_in[14];
  const float* bnf_g = (const float*)d_in[15];
  const float* bnf_b = (const float*)d_in[16];
  const float* bnc_g = (const float*)d_in[17];
  const float* bnc_b = (const float*)d_in[18];
  const float* bno_g = (const float*)d_in[19];
  const float* bno_b = (const float*)d_in[20];
  const float* l2_w = (const float*)d_in[21];
  const float* l2_b = (const float*)d_in[22];
  const float* out_w = (const float*)d_in[23];
  const float* out_b = (const float*)d_in[24];

  // workspace layout (bytes, 256-aligned)
  char* base = (char*)d_ws;
  size_t off = 0;
  auto alloc = [&](size_t bytes) {
    size_t o = off;
    off = (off + bytes + 255) & ~(size_t)255;
    return o;
  };
  unsigned short* xbf = (unsigned short*)(base + alloc((size_t)N_NODES * 64 * 2));
  unsigned short* hab = (unsigned short*)(base + alloc((size_t)N_HEDGES * 35 * 2));
  unsigned* Vfc = (unsigned*)(base + alloc((size_t)N_HEDGES * 64 * 4));
  unsigned short* zbuf = (unsigned short*)(base + alloc((size_t)N_HEDGES * 72 * 2));
  unsigned short* obuf = (unsigned short*)(base + alloc((size_t)N_NODES * 64 * 2));
  unsigned* Ufc = (unsigned*)(base + alloc((size_t)N_NODES * 64 * 4));
  uint4* wpk = (uint4*)(base + alloc((size_t)60 * 64 * 16));
  float* hstatsA = (float*)(base + alloc(3 * 160 * 4));
  float* ostatsA = (float*)(base + alloc(3 * 128 * 4));
  float* pooled = (float*)(base + alloc((size_t)N_GRAPHS * 64 * 4));
  float* gcnt = (float*)(base + alloc((size_t)N_GRAPHS * 4));
  int* degH = (int*)(base + alloc((size_t)N_HEDGES * 4));  // degH|degN adjacent memset
  int* degN = (int*)(base + alloc((size_t)N_NODES * 4));
  int* offH = (int*)(base + alloc((size_t)(N_HEDGES + 1) * 4));  // +1 sentinel
  int* offN = (int*)(base + alloc((size_t)(N_NODES + 1) * 4));   // +1 sentinel
  float* invdH = (float*)(base + alloc((size_t)N_HEDGES * 4));
  float* invdN = (float*)(base + alloc((size_t)N_NODES * 4));
  int* bsum = (int*)(base + alloc((size_t)(CHB + CNB) * 4));
  int* rankH = (int*)(base + alloc((size_t)N_INC * 4));
  int* rankN = (int*)(base + alloc((size_t)N_INC * 4));
  int* permHn = (int*)(base + alloc((size_t)N_INC * 4));
  int* permNh = (int*)(base + alloc((size_t)N_INC * 4));
  (void)ws_size;
  (void)in_sizes;
  (void)n_in;
  (void)out_size;

  // ---- ordered CSR build ----
  hipMemsetAsync(degH, 0,
                 (size_t)((char*)degN - (char*)degH) + (size_t)N_NODES * 4, stream);
  k_hist<<<(N_INC + 255) / 256, 256, 0, stream>>>(node_idx, hedge_idx, degN, degH,
                                                  rankN, rankH);
  k_bsum<<<CHB + CNB, 256, 0, stream>>>(degH, degN, bsum);
  k_bscan<<<2, 64, 0, stream>>>(bsum);
  k_alloc2<<<CHB + CNB, 256, 0, stream>>>(degH, degN, bsum, offH, offN, invdH, invdN);
  k_fill<<<(N_INC + 255) / 256, 256, 0, stream>>>(node_idx, hedge_idx, rankH, rankN,
                                                  offH, offN, permHn, permNh,
                                                  &offH[N_HEDGES], &offN[N_NODES]);
  k_wpack<<<60, 64, 0, stream>>>(f1_w, c1_w, wpk);
  k_embed<<<N_NODES / 16, 256, 0, stream>>>(x_in, embed_w, embed_b, xbf);

  // zero all per-layer stats in one go
  hipMemsetAsync(hstatsA, 0, (size_t)((char*)ostatsA - (char*)hstatsA) + 3 * 128 * 4,
                 stream);

  // layer-0 U projection (layers 1,2 fused into k_update_uv)
  k_uv_node<<<N_NODES / 16, 256, 0, stream>>>(xbf, f2_w, c2_w, Ufc);

  for (int i = 0; i < 3; ++i) {
    float* hstats = hstatsA + i * 160;
    float* ostats = ostatsA + i * 128;

    // fused pipelined gather + MFMA GEMM + stats
    if (i == 0)
      k_hedge_gemm<true><<<N_HEDGES / GR, 256, 0, stream>>>(
          xbf, permHn, offH, invdH, hab, hedge_attr, wpk, zbuf, hstats);
    else
      k_hedge_gemm<false><<<N_HEDGES / GR, 256, 0, stream>>>(
          xbf, permHn, offH, invdH, hab, hedge_attr, wpk + (size_t)i * 20 * 64, zbuf,
          hstats);
    // fused BN+act -> ha + V-projection (skip dead hab write on last layer)
    k_hedge_post<<<N_HEDGES / 16, 256, 0, stream>>>(
        zbuf, hstats, bnf_g + i * HE, bnf_b + i * HE, bnc_g + i * HE, bnc_b + i * HE,
        f2_w + i * CAT * 64 + 64 * 64, c2_w + i * CAT * 64 + 64 * 64,
        f2_b + i * 64, c2_b + i * 64, hab, Vfc, (i < 2) ? 1 : 0);

    // per-node combine (linear-entry chunked walk) + fused BN stats
    k_node_aggr<<<(N_NODES + 63) / 64, 256, 0, stream>>>(permNh, offN, invdN, Ufc,
                                                         Vfc, obuf, ostats);

    // node BN + residual softplus (+ next layer's U projection fused)
    if (i < 2)
      k_update_uv<<<N_NODES / 16, 256, 0, stream>>>(
          xbf, obuf, ostats, bno_g + i * 64, bno_b + i * 64,
          f2_w + (i + 1) * CAT * 64, c2_w + (i + 1) * CAT * 64, Ufc);
    else
      k_update<<<N_NODES * 64 / 256, 256, 0, stream>>>(xbf, obuf, ostats,
                                                       bno_g + i * 64,
                                                       bno_b + i * 64);
  }

  // pooling + head
  hipMemsetAsync(pooled, 0, (size_t)((char*)gcnt - (char*)pooled) + N_GRAPHS * 4,
                 stream);
  k_pool<<<(N_NODES + PR - 1) / PR, 256, 0, stream>>>(xbf, batch, pooled, gcnt);
  k_final<<<N_GRAPHS, 128, 0, stream>>>(pooled, gcnt, l2_w, l2_b, out_w, out_b,
                                        (float*)d_out);
}